// Round 5
// baseline (9307.219 us; speedup 1.0000x reference)
//
#include <hip/hip_runtime.h>

#define NB 16
#define RING 64

__device__ __forceinline__ float sig_(float x) { return 1.0f / (1.0f + __expf(-x)); }
__device__ __forceinline__ float th_(float x)  { return 1.0f - 2.0f / (__expf(2.0f * x) + 1.0f); }

// ---------------------------------------------------------------------------
// Fused NT GEMM: acc[m][g*256+j] = sum_k A[m][k] * Wt[g*256+j][k]
// grid (ceil(M/64), 4), block 256. Tile: 64 m x 64 h-idx (x4 gates = 256 cols).
// mode 0/2: Cout = acc + bias      (emb2 build / gatesB build)
// mode 1:   LSTM token step t: gates = acc + emb2[tok[m][t]]; c,h update,
//           conditional instr_feats write.
// ---------------------------------------------------------------------------
__global__ __launch_bounds__(256, 2)
void gemm_fused(const float* __restrict__ A, const float* __restrict__ Wt,
                const float* __restrict__ bias, float* __restrict__ Cout,
                int M, int mode,
                const int* __restrict__ tok, int t, const float* __restrict__ emb2,
                const int* __restrict__ lengths, float* __restrict__ cbuf,
                float* __restrict__ hout, float* __restrict__ feats)
{
    __shared__ float a_lds[32][64];       // [k][m]
    __shared__ float b_lds[4][32][64];    // [gate][k][r]
    const int tid = threadIdx.x;
    const int tn = tid & 15;              // -> 4 m rows
    const int th = tid >> 4;              // -> 4 h cols
    const int m0 = blockIdx.x * 64;
    const int j0 = blockIdx.y * 64;

    float acc[4][4][4];                   // [gate][hi][ni]
    #pragma unroll
    for (int g = 0; g < 4; ++g)
        #pragma unroll
        for (int x = 0; x < 4; ++x)
            #pragma unroll
            for (int y = 0; y < 4; ++y) acc[g][x][y] = 0.f;

    float4 abuf[2], bbuf[8];
    auto load_t = [&](int k0) {
        #pragma unroll
        for (int p = 0; p < 2; ++p) {
            int idx = tid + p * 256, ml = idx >> 3, k4 = idx & 7;
            int row = m0 + ml;
            abuf[p] = (row < M) ? *(const float4*)&A[row * 256 + k0 + k4 * 4]
                                : make_float4(0.f, 0.f, 0.f, 0.f);
        }
        #pragma unroll
        for (int p = 0; p < 8; ++p) {
            int idx = tid + p * 256;
            int g = idx >> 9, rem = idx & 511, r = rem >> 3, k4 = rem & 7;
            bbuf[p] = *(const float4*)&Wt[(g * 256 + j0 + r) * 256 + k0 + k4 * 4];
        }
    };
    auto store_t = [&]() {
        #pragma unroll
        for (int p = 0; p < 2; ++p) {
            int idx = tid + p * 256, ml = idx >> 3, k4 = idx & 7;
            a_lds[k4 * 4 + 0][ml] = abuf[p].x;
            a_lds[k4 * 4 + 1][ml] = abuf[p].y;
            a_lds[k4 * 4 + 2][ml] = abuf[p].z;
            a_lds[k4 * 4 + 3][ml] = abuf[p].w;
        }
        #pragma unroll
        for (int p = 0; p < 8; ++p) {
            int idx = tid + p * 256;
            int g = idx >> 9, rem = idx & 511, r = rem >> 3, k4 = rem & 7;
            b_lds[g][k4 * 4 + 0][r] = bbuf[p].x;
            b_lds[g][k4 * 4 + 1][r] = bbuf[p].y;
            b_lds[g][k4 * 4 + 2][r] = bbuf[p].z;
            b_lds[g][k4 * 4 + 3][r] = bbuf[p].w;
        }
    };

    load_t(0); store_t(); __syncthreads();
    for (int c = 0; c < 8; ++c) {
        if (c < 7) load_t((c + 1) * 32);  // reg double-buffer: hide global latency
        #pragma unroll 8
        for (int k = 0; k < 32; ++k) {
            float4 a4 = *(const float4*)&a_lds[k][tn * 4];
            float av[4] = {a4.x, a4.y, a4.z, a4.w};
            #pragma unroll
            for (int g = 0; g < 4; ++g) {
                float4 b4 = *(const float4*)&b_lds[g][k][th * 4];
                float bv[4] = {b4.x, b4.y, b4.z, b4.w};
                #pragma unroll
                for (int hi = 0; hi < 4; ++hi)
                    #pragma unroll
                    for (int ni = 0; ni < 4; ++ni)
                        acc[g][hi][ni] += bv[hi] * av[ni];
            }
        }
        __syncthreads();
        if (c < 7) { store_t(); __syncthreads(); }
    }

    const int colb = j0 + th * 4;
    if (mode != 1) {
        float4 bs[4];
        #pragma unroll
        for (int g = 0; g < 4; ++g) bs[g] = *(const float4*)&bias[g * 256 + colb];
        #pragma unroll
        for (int ni = 0; ni < 4; ++ni) {
            int row = m0 + tn * 4 + ni;
            if (row < M) {
                #pragma unroll
                for (int g = 0; g < 4; ++g) {
                    float4 o;
                    o.x = acc[g][0][ni] + bs[g].x;
                    o.y = acc[g][1][ni] + bs[g].y;
                    o.z = acc[g][2][ni] + bs[g].z;
                    o.w = acc[g][3][ni] + bs[g].w;
                    *(float4*)&Cout[row * 1024 + g * 256 + colb] = o;
                }
            }
        }
    } else {
        #pragma unroll
        for (int ni = 0; ni < 4; ++ni) {
            int n = m0 + tn * 4 + ni;
            int v = tok[n * 16 + t];
            const float* e = emb2 + v * 1024 + colb;
            float4 e0 = *(const float4*)(e);
            float4 e1 = *(const float4*)(e + 256);
            float4 e2 = *(const float4*)(e + 512);
            float4 e3 = *(const float4*)(e + 768);
            float4 co = *(const float4*)&cbuf[n * 256 + colb];
            float eg[4][4] = {{e0.x, e0.y, e0.z, e0.w}, {e1.x, e1.y, e1.z, e1.w},
                              {e2.x, e2.y, e2.z, e2.w}, {e3.x, e3.y, e3.z, e3.w}};
            float cold[4] = {co.x, co.y, co.z, co.w};
            float cn[4], hn[4];
            #pragma unroll
            for (int hi = 0; hi < 4; ++hi) {
                float ig = acc[0][hi][ni] + eg[0][hi];
                float fg = acc[1][hi][ni] + eg[1][hi];
                float gg = acc[2][hi][ni] + eg[2][hi];
                float og = acc[3][hi][ni] + eg[3][hi];
                float cc = sig_(fg) * cold[hi] + sig_(ig) * th_(gg);
                cn[hi] = cc;
                hn[hi] = sig_(og) * th_(cc);
            }
            float4 c4 = make_float4(cn[0], cn[1], cn[2], cn[3]);
            float4 h4 = make_float4(hn[0], hn[1], hn[2], hn[3]);
            *(float4*)&cbuf[n * 256 + colb] = c4;
            *(float4*)&hout[n * 256 + colb] = h4;
            if (lengths[n] == t + 1) *(float4*)&feats[n * 256 + colb] = h4;
        }
    }
}

// ---------------------------------------------------------------------------
// Token-LSTM step 0 (h0 = c0 = 0 -> pure pointwise from emb2 gather)
// ---------------------------------------------------------------------------
__global__ __launch_bounds__(256)
void step0_kernel(const int* __restrict__ tok, const int* __restrict__ lengths,
                  const float* __restrict__ emb2, float* __restrict__ cbuf,
                  float* __restrict__ h0, float* __restrict__ feats)
{
    int n = blockIdx.x, j = threadIdx.x;
    int v = tok[n * 16];
    const float* e = emb2 + v * 1024;
    float ig = e[j], gg = e[512 + j], og = e[768 + j];
    float c = sig_(ig) * th_(gg);          // f-gate * c0 drops (c0 = 0)
    float h = sig_(og) * th_(c);
    cbuf[n * 256 + j] = c;
    h0[n * 256 + j] = h;
    if (lengths[n] == 1) feats[n * 256 + j] = h;
}

// ---------------------------------------------------------------------------
// Instruction-LSTM scan, COLUMN-PARTITIONED edition.
// Block b owns h[16b..16b+16) and W_hh columns [16b..16b+16) for ALL 1024
// rows (64 KB -> 64 VGPRs/thread). Per step it publishes partial sums
// P_b[r] = sum_{j in own} W[r][j] h[j] for all rows, grouped by consumer:
// Pring[slot][j=b][c][r'], r' = g*16+i2. Consumers sum 16 partials per row
// (4 polled loads + 2 shfl), gather 4 gates in-wave (round-3 lane trick),
// activate, broadcast 16 h via double-buffered LDS (ONE barrier/step),
// compute own partial (~130 cyc), store. Heavy matvec is OFF the serial
// critical path; each polled line has 16 pollers (was ~240).
// Ring depth 64; consumer resets its read-once words after detection
// (same-address program order keeps reset after final poll load; producer
// reuses the slot 63 steps later).
// Lane map: l = g*16 + i4*4 + jq; wave w handles i2 = w*4+i4, all 4 gates.
// ---------------------------------------------------------------------------
__global__ __launch_bounds__(256, 1)
void scan_kernel(const float* __restrict__ gatesB, const float* __restrict__ Whh,
                 const float* __restrict__ linW, const float* __restrict__ linb,
                 float* __restrict__ Pring, float* __restrict__ hT,
                 float* __restrict__ out)
{
    const int b   = blockIdx.x;
    const int tid = threadIdx.x;
    const int w   = tid >> 6;             // wave
    const int l   = tid & 63;
    const int g   = l >> 4;               // gate
    const int i4  = (l >> 2) & 3;         // h-index within wave
    const int jq  = l & 3;                // j-quad for partial summation
    const int i2  = w * 4 + i4;           // h sub-index within block
    // producer map: thread covers 4 consecutive rows of one consumer group
    const int ct  = tid >> 4;             // consumer block 0..15
    const int rr  = (tid & 15) * 4;       // r' base (stays within one gate)
    const int pg  = rr >> 4;              // gate of those rows
    const int pi0 = rr & 15;              // i2 base of those rows

    __shared__ float h_own2[2][16];       // double-buffered own-h broadcast
    __shared__ float red_lds[4];

    // W2: rows pg*256 + ct*16 + pi0+k (k=0..3), own cols b*16..b*16+16
    float4 w2[4][4];
    #pragma unroll
    for (int k = 0; k < 4; ++k) {
        const float* wp = Whh + (pg * 256 + ct * 16 + pi0 + k) * 256 + b * 16;
        #pragma unroll
        for (int q4 = 0; q4 < 4; ++q4) w2[k][q4] = *(const float4*)&wp[q4 * 4];
    }

    float c_reg = 0.f;                    // c state for i2 (16x replicated)
    float hh = 0.f;
    const int rprime = g * 16 + i2;
    unsigned* const pb32 = (unsigned*)Pring;

    for (int s = 0; s < 4096; ++s) {
        // bias prefetch: independent of partials, issues before polls
        float bias = gatesB[s * 1024 + g * 256 + b * 16 + i2];
        float gsum = 0.f;
        if (s > 0) {
            const int cslot = (s - 1) & (RING - 1);
            unsigned* p0 = pb32 + cslot * 16384 + (jq * 4) * 1024 + b * 64 + rprime;
            unsigned* p1 = p0 + 1024;
            unsigned* p2 = p0 + 2048;
            unsigned* p3 = p0 + 3072;
            unsigned u0 = __hip_atomic_load(p0, __ATOMIC_RELAXED, __HIP_MEMORY_SCOPE_AGENT);
            unsigned u1 = __hip_atomic_load(p1, __ATOMIC_RELAXED, __HIP_MEMORY_SCOPE_AGENT);
            unsigned u2 = __hip_atomic_load(p2, __ATOMIC_RELAXED, __HIP_MEMORY_SCOPE_AGENT);
            unsigned u3 = __hip_atomic_load(p3, __ATOMIC_RELAXED, __HIP_MEMORY_SCOPE_AGENT);
            while ((u0 == 0xFFFFFFFFu) || (u1 == 0xFFFFFFFFu) ||
                   (u2 == 0xFFFFFFFFu) || (u3 == 0xFFFFFFFFu)) {
                __builtin_amdgcn_s_sleep(1);
                if (u0 == 0xFFFFFFFFu)
                    u0 = __hip_atomic_load(p0, __ATOMIC_RELAXED, __HIP_MEMORY_SCOPE_AGENT);
                if (u1 == 0xFFFFFFFFu)
                    u1 = __hip_atomic_load(p1, __ATOMIC_RELAXED, __HIP_MEMORY_SCOPE_AGENT);
                if (u2 == 0xFFFFFFFFu)
                    u2 = __hip_atomic_load(p2, __ATOMIC_RELAXED, __HIP_MEMORY_SCOPE_AGENT);
                if (u3 == 0xFFFFFFFFu)
                    u3 = __hip_atomic_load(p3, __ATOMIC_RELAXED, __HIP_MEMORY_SCOPE_AGENT);
            }
            // reset read-once words for ring reuse (63-step cushion)
            __hip_atomic_store(p0, 0xFFFFFFFFu, __ATOMIC_RELAXED, __HIP_MEMORY_SCOPE_AGENT);
            __hip_atomic_store(p1, 0xFFFFFFFFu, __ATOMIC_RELAXED, __HIP_MEMORY_SCOPE_AGENT);
            __hip_atomic_store(p2, 0xFFFFFFFFu, __ATOMIC_RELAXED, __HIP_MEMORY_SCOPE_AGENT);
            __hip_atomic_store(p3, 0xFFFFFFFFu, __ATOMIC_RELAXED, __HIP_MEMORY_SCOPE_AGENT);
            gsum = __uint_as_float(u0) + __uint_as_float(u1)
                 + __uint_as_float(u2) + __uint_as_float(u3);
            gsum += __shfl_xor(gsum, 1);
            gsum += __shfl_xor(gsum, 2);  // full 16-j sum in all jq lanes
        }
        float gate = gsum + bias;
        // gather i,f,g,o for my i2 (in-wave; no LDS, no barrier)
        float igv = __shfl(gate,      i4 * 4);
        float fgv = __shfl(gate, 16 + i4 * 4);
        float ggv = __shfl(gate, 32 + i4 * 4);
        float ogv = __shfl(gate, 48 + i4 * 4);
        float cc = sig_(fgv) * c_reg + sig_(igv) * th_(ggv);
        c_reg = cc;
        hh = sig_(ogv) * th_(cc);
        const int pb = (s + 1) & 1;
        if ((l & 51) == 0) h_own2[pb][i2] = hh;   // g==0 && jq==0 lanes
        __syncthreads();                  // the ONE barrier per step
        if (s < 4095) {
            float4 ho0 = *(const float4*)&h_own2[pb][0];
            float4 ho1 = *(const float4*)&h_own2[pb][4];
            float4 ho2 = *(const float4*)&h_own2[pb][8];
            float4 ho3 = *(const float4*)&h_own2[pb][12];
            const int slot = s & (RING - 1);
            float* dst = Pring + slot * 16384 + b * 1024 + ct * 64 + rr;
            #pragma unroll
            for (int k = 0; k < 4; ++k) {
                float pk = w2[k][0].x * ho0.x + w2[k][0].y * ho0.y
                         + w2[k][0].z * ho0.z + w2[k][0].w * ho0.w
                         + w2[k][1].x * ho1.x + w2[k][1].y * ho1.y
                         + w2[k][1].z * ho1.z + w2[k][1].w * ho1.w
                         + w2[k][2].x * ho2.x + w2[k][2].y * ho2.y
                         + w2[k][2].z * ho2.z + w2[k][2].w * ho2.w
                         + w2[k][3].x * ho3.x + w2[k][3].y * ho3.y
                         + w2[k][3].z * ho3.z + w2[k][3].w * ho3.w;
                __hip_atomic_store(&dst[k], pk, __ATOMIC_RELAXED,
                                   __HIP_MEMORY_SCOPE_AGENT);
            }
        }
    }

    // publish h_T words (data-as-flag), block 0 reduces
    if ((l & 51) == 0)
        __hip_atomic_store(&hT[b * 16 + i2], hh, __ATOMIC_RELAXED,
                           __HIP_MEMORY_SCOPE_AGENT);
    if (b == 0) {
        unsigned* hp = (unsigned*)&hT[tid];
        unsigned u = __hip_atomic_load(hp, __ATOMIC_RELAXED, __HIP_MEMORY_SCOPE_AGENT);
        while (u == 0xFFFFFFFFu) {
            __builtin_amdgcn_s_sleep(1);
            u = __hip_atomic_load(hp, __ATOMIC_RELAXED, __HIP_MEMORY_SCOPE_AGENT);
        }
        float p = __uint_as_float(u) * linW[tid];
        #pragma unroll
        for (int off = 1; off < 64; off <<= 1) p += __shfl_xor(p, off);
        if (l == 0) red_lds[w] = p;
        __syncthreads();
        if (tid == 0)
            out[0] = red_lds[0] + red_lds[1] + red_lds[2] + red_lds[3] + linb[0];
    }
}

extern "C" void kernel_launch(void* const* d_in, const int* in_sizes, int n_in,
                              void* d_out, int out_size, void* d_ws, size_t ws_size,
                              hipStream_t stream)
{
    const int*   tok  = (const int*)d_in[0];
    const int*   len  = (const int*)d_in[1];
    const float* emb  = (const float*)d_in[2];
    const float* tWih = (const float*)d_in[3];
    const float* tWhh = (const float*)d_in[4];
    const float* tb   = (const float*)d_in[5];
    const float* iWih = (const float*)d_in[6];
    const float* iWhh = (const float*)d_in[7];
    const float* ib   = (const float*)d_in[8];
    const float* lW   = (const float*)d_in[9];
    const float* lb   = (const float*)d_in[10];
    float* out = (float*)d_out;

    // workspace layout (floats): ~46 MiB total
    float* emb2   = (float*)d_ws;           // [2000][1024]
    float* hbuf0  = emb2  + 2048000;        // [4096][256] ping
    float* hbuf1  = hbuf0 + 1048576;        // [4096][256] pong
    float* cbuf   = hbuf1 + 1048576;        // [4096][256]
    float* feats  = cbuf  + 1048576;        // [4096][256]
    float* gatesB = feats + 1048576;        // [4096][1024]
    float* Pring  = gatesB + 4194304;       // [64][16][16][64] partial ring, 4 MB
    float* hT     = Pring + 1048576;        // [256] final-h data-as-flag

    // sentinel init: 0xFF bytes -> 0xFFFFFFFF (-NaN) in Pring and hT
    hipMemsetAsync(Pring, 0xFF, (size_t)(1048576 + 256) * sizeof(float), stream);

    // emb2 = emb @ tok_W_ih^T + tok_b  (V=2000 rows)
    gemm_fused<<<dim3(32, 4), 256, 0, stream>>>(emb, tWih, tb, emb2, 2000, 0,
                                                nullptr, 0, nullptr, nullptr,
                                                nullptr, nullptr, nullptr);
    // token LSTM step 0 (pointwise)
    step0_kernel<<<4096, 256, 0, stream>>>(tok, len, emb2, cbuf, hbuf0, feats);
    // token LSTM steps 1..15 (fused GEMM + gather + activations)
    for (int t = 1; t < 16; ++t) {
        float* hprev = (t & 1) ? hbuf0 : hbuf1;
        float* hcur  = (t & 1) ? hbuf1 : hbuf0;
        gemm_fused<<<dim3(64, 4), 256, 0, stream>>>(hprev, tWhh, nullptr, nullptr,
                                                    4096, 1, tok, t, emb2, len,
                                                    cbuf, hcur, feats);
    }
    // gatesB = instr_feats @ ins_W_ih^T + ins_b
    gemm_fused<<<dim3(64, 4), 256, 0, stream>>>(feats, iWih, ib, gatesB, 4096, 2,
                                                nullptr, 0, nullptr, nullptr,
                                                nullptr, nullptr, nullptr);
    // 4096-step sequential instruction LSTM + final linear
    scan_kernel<<<NB, 256, 0, stream>>>(gatesB, iWhh, lW, lb, Pring, hT, out);
}

// Round 6
// 2558.104 us; speedup vs baseline: 3.6383x; 3.6383x over previous
//
#include <hip/hip_runtime.h>

#define SWEEPS 30
#define HSTRIDE 4112   // hT row stride: 4096 + front pad(1) + slack, %4==0

__device__ __forceinline__ float sig_(float x) { return 1.0f / (1.0f + __expf(-x)); }
__device__ __forceinline__ float th_(float x)  { return 1.0f - 2.0f / (__expf(2.0f * x) + 1.0f); }

// ---------------------------------------------------------------------------
// Fused NT GEMM: acc[m][g*256+j] = sum_k A[m][k] * Wt[g*256+j][k]
// grid (ceil(M/64), 4), block 256. Tile: 64 m x 64 h-idx (x4 gates = 256 cols).
// mode 0: Cout = acc + bias                       (emb2 build)
// mode 1: LSTM token step t (gather + activations + feats write)
// mode 3: Cout TRANSPOSED [r][4096] = acc + bias  (gBT build for sweeps)
// ---------------------------------------------------------------------------
__global__ __launch_bounds__(256, 2)
void gemm_fused(const float* __restrict__ A, const float* __restrict__ Wt,
                const float* __restrict__ bias, float* __restrict__ Cout,
                int M, int mode,
                const int* __restrict__ tok, int t, const float* __restrict__ emb2,
                const int* __restrict__ lengths, float* __restrict__ cbuf,
                float* __restrict__ hout, float* __restrict__ feats)
{
    __shared__ float a_lds[32][64];       // [k][m]
    __shared__ float b_lds[4][32][64];    // [gate][k][r]
    const int tid = threadIdx.x;
    const int tn = tid & 15;              // -> 4 m rows
    const int th = tid >> 4;              // -> 4 h cols
    const int m0 = blockIdx.x * 64;
    const int j0 = blockIdx.y * 64;

    float acc[4][4][4];                   // [gate][hi][ni]
    #pragma unroll
    for (int g = 0; g < 4; ++g)
        #pragma unroll
        for (int x = 0; x < 4; ++x)
            #pragma unroll
            for (int y = 0; y < 4; ++y) acc[g][x][y] = 0.f;

    float4 abuf[2], bbuf[8];
    auto load_t = [&](int k0) {
        #pragma unroll
        for (int p = 0; p < 2; ++p) {
            int idx = tid + p * 256, ml = idx >> 3, k4 = idx & 7;
            int row = m0 + ml;
            abuf[p] = (row < M) ? *(const float4*)&A[row * 256 + k0 + k4 * 4]
                                : make_float4(0.f, 0.f, 0.f, 0.f);
        }
        #pragma unroll
        for (int p = 0; p < 8; ++p) {
            int idx = tid + p * 256;
            int g = idx >> 9, rem = idx & 511, r = rem >> 3, k4 = rem & 7;
            bbuf[p] = *(const float4*)&Wt[(g * 256 + j0 + r) * 256 + k0 + k4 * 4];
        }
    };
    auto store_t = [&]() {
        #pragma unroll
        for (int p = 0; p < 2; ++p) {
            int idx = tid + p * 256, ml = idx >> 3, k4 = idx & 7;
            a_lds[k4 * 4 + 0][ml] = abuf[p].x;
            a_lds[k4 * 4 + 1][ml] = abuf[p].y;
            a_lds[k4 * 4 + 2][ml] = abuf[p].z;
            a_lds[k4 * 4 + 3][ml] = abuf[p].w;
        }
        #pragma unroll
        for (int p = 0; p < 8; ++p) {
            int idx = tid + p * 256;
            int g = idx >> 9, rem = idx & 511, r = rem >> 3, k4 = rem & 7;
            b_lds[g][k4 * 4 + 0][r] = bbuf[p].x;
            b_lds[g][k4 * 4 + 1][r] = bbuf[p].y;
            b_lds[g][k4 * 4 + 2][r] = bbuf[p].z;
            b_lds[g][k4 * 4 + 3][r] = bbuf[p].w;
        }
    };

    load_t(0); store_t(); __syncthreads();
    for (int c = 0; c < 8; ++c) {
        if (c < 7) load_t((c + 1) * 32);  // reg double-buffer: hide global latency
        #pragma unroll 8
        for (int k = 0; k < 32; ++k) {
            float4 a4 = *(const float4*)&a_lds[k][tn * 4];
            float av[4] = {a4.x, a4.y, a4.z, a4.w};
            #pragma unroll
            for (int g = 0; g < 4; ++g) {
                float4 b4 = *(const float4*)&b_lds[g][k][th * 4];
                float bv[4] = {b4.x, b4.y, b4.z, b4.w};
                #pragma unroll
                for (int hi = 0; hi < 4; ++hi)
                    #pragma unroll
                    for (int ni = 0; ni < 4; ++ni)
                        acc[g][hi][ni] += bv[hi] * av[ni];
            }
        }
        __syncthreads();
        if (c < 7) { store_t(); __syncthreads(); }
    }

    const int colb = j0 + th * 4;
    if (mode == 0) {
        float4 bs[4];
        #pragma unroll
        for (int g = 0; g < 4; ++g) bs[g] = *(const float4*)&bias[g * 256 + colb];
        #pragma unroll
        for (int ni = 0; ni < 4; ++ni) {
            int row = m0 + tn * 4 + ni;
            if (row < M) {
                #pragma unroll
                for (int g = 0; g < 4; ++g) {
                    float4 o;
                    o.x = acc[g][0][ni] + bs[g].x;
                    o.y = acc[g][1][ni] + bs[g].y;
                    o.z = acc[g][2][ni] + bs[g].z;
                    o.w = acc[g][3][ni] + bs[g].w;
                    *(float4*)&Cout[row * 1024 + g * 256 + colb] = o;
                }
            }
        }
    } else if (mode == 3) {
        // transposed store: Cout[r][s], r = g*256+colb+hi, s = m0+tn*4+ni
        float4 bs[4];
        #pragma unroll
        for (int g = 0; g < 4; ++g) bs[g] = *(const float4*)&bias[g * 256 + colb];
        const int row0 = m0 + tn * 4;
        #pragma unroll
        for (int g = 0; g < 4; ++g) {
            const float* bsp = (const float*)&bs[g];
            #pragma unroll
            for (int hi = 0; hi < 4; ++hi) {
                float4 o;
                o.x = acc[g][hi][0] + bsp[hi];
                o.y = acc[g][hi][1] + bsp[hi];
                o.z = acc[g][hi][2] + bsp[hi];
                o.w = acc[g][hi][3] + bsp[hi];
                *(float4*)&Cout[(g * 256 + colb + hi) * 4096 + row0] = o;
            }
        }
    } else {
        #pragma unroll
        for (int ni = 0; ni < 4; ++ni) {
            int n = m0 + tn * 4 + ni;
            int v = tok[n * 16 + t];
            const float* e = emb2 + v * 1024 + colb;
            float4 e0 = *(const float4*)(e);
            float4 e1 = *(const float4*)(e + 256);
            float4 e2 = *(const float4*)(e + 512);
            float4 e3 = *(const float4*)(e + 768);
            float4 co = *(const float4*)&cbuf[n * 256 + colb];
            float eg[4][4] = {{e0.x, e0.y, e0.z, e0.w}, {e1.x, e1.y, e1.z, e1.w},
                              {e2.x, e2.y, e2.z, e2.w}, {e3.x, e3.y, e3.z, e3.w}};
            float cold[4] = {co.x, co.y, co.z, co.w};
            float cn[4], hn[4];
            #pragma unroll
            for (int hi = 0; hi < 4; ++hi) {
                float ig = acc[0][hi][ni] + eg[0][hi];
                float fg = acc[1][hi][ni] + eg[1][hi];
                float gg = acc[2][hi][ni] + eg[2][hi];
                float og = acc[3][hi][ni] + eg[3][hi];
                float cc = sig_(fg) * cold[hi] + sig_(ig) * th_(gg);
                cn[hi] = cc;
                hn[hi] = sig_(og) * th_(cc);
            }
            float4 c4 = make_float4(cn[0], cn[1], cn[2], cn[3]);
            float4 h4 = make_float4(hn[0], hn[1], hn[2], hn[3]);
            *(float4*)&cbuf[n * 256 + colb] = c4;
            *(float4*)&hout[n * 256 + colb] = h4;
            if (lengths[n] == t + 1) *(float4*)&feats[n * 256 + colb] = h4;
        }
    }
}

// ---------------------------------------------------------------------------
// Token-LSTM step 0 (h0 = c0 = 0 -> pure pointwise from emb2 gather)
// ---------------------------------------------------------------------------
__global__ __launch_bounds__(256)
void step0_kernel(const int* __restrict__ tok, const int* __restrict__ lengths,
                  const float* __restrict__ emb2, float* __restrict__ cbuf,
                  float* __restrict__ h0, float* __restrict__ feats)
{
    int n = blockIdx.x, j = threadIdx.x;
    int v = tok[n * 16];
    const float* e = emb2 + v * 1024;
    float ig = e[j], gg = e[512 + j], og = e[768 + j];
    float c = sig_(ig) * th_(gg);          // f-gate * c0 drops (c0 = 0)
    float h = sig_(og) * th_(c);
    cbuf[n * 256 + j] = c;
    h0[n * 256 + j] = h;
    if (lengths[n] == 1) feats[n * 256 + j] = h;
}

// ---------------------------------------------------------------------------
// Sweep GEMM: ZT[r][s] = sum_k Whh[r][k] * hT[k][s-1] + gBT[r][s]
// hT layout: hTbuf[k*HSTRIDE + 1 + s], col 0 == 0  ->  hT[k][s-1] is simply
// hTbuf[k*HSTRIDE + s] (the front pad absorbs the shift; stays f4-aligned).
// grid (4096/64, 1024/64) = (64,16), block 256, tile 64r x 64s, K=256.
// ---------------------------------------------------------------------------
__global__ __launch_bounds__(256, 4)
void gemm_zT(const float* __restrict__ Whh, const float* __restrict__ hTbuf,
             const float* __restrict__ gBT, float* __restrict__ ZT)
{
    __shared__ float w_lds[32][68];       // [k][r]
    __shared__ float h_lds[32][68];       // [k][s]
    const int tid = threadIdx.x;
    const int tr = tid & 15;              // -> 4 r
    const int ts = tid >> 4;              // -> 4 s
    const int s0 = blockIdx.x * 64;
    const int r0 = blockIdx.y * 64;

    float acc[4][4];                      // [ri][si]
    #pragma unroll
    for (int x = 0; x < 4; ++x)
        #pragma unroll
        for (int y = 0; y < 4; ++y) acc[x][y] = 0.f;

    float4 wbuf[2], hbuf[2];
    auto load_t = [&](int k0) {
        #pragma unroll
        for (int p = 0; p < 2; ++p) {
            int idx = tid + p * 256;
            int r = idx >> 3, k4 = idx & 7;
            wbuf[p] = *(const float4*)&Whh[(r0 + r) * 256 + k0 + k4 * 4];
            int j = idx >> 4, s4 = idx & 15;
            hbuf[p] = *(const float4*)&hTbuf[(k0 + j) * HSTRIDE + s0 + s4 * 4];
        }
    };
    auto store_t = [&]() {
        #pragma unroll
        for (int p = 0; p < 2; ++p) {
            int idx = tid + p * 256;
            int r = idx >> 3, k4 = idx & 7;
            w_lds[k4 * 4 + 0][r] = wbuf[p].x;
            w_lds[k4 * 4 + 1][r] = wbuf[p].y;
            w_lds[k4 * 4 + 2][r] = wbuf[p].z;
            w_lds[k4 * 4 + 3][r] = wbuf[p].w;
            int j = idx >> 4, s4 = idx & 15;
            *(float4*)&h_lds[j][s4 * 4] = hbuf[p];
        }
    };

    load_t(0); store_t(); __syncthreads();
    for (int c = 0; c < 8; ++c) {
        if (c < 7) load_t((c + 1) * 32);
        #pragma unroll 8
        for (int k = 0; k < 32; ++k) {
            float4 wv = *(const float4*)&w_lds[k][tr * 4];
            float4 hv = *(const float4*)&h_lds[k][ts * 4];
            float wa[4] = {wv.x, wv.y, wv.z, wv.w};
            float ha[4] = {hv.x, hv.y, hv.z, hv.w};
            #pragma unroll
            for (int ri = 0; ri < 4; ++ri)
                #pragma unroll
                for (int si = 0; si < 4; ++si)
                    acc[ri][si] += wa[ri] * ha[si];
        }
        __syncthreads();
        if (c < 7) { store_t(); __syncthreads(); }
    }

    const int scol = s0 + ts * 4;
    #pragma unroll
    for (int ri = 0; ri < 4; ++ri) {
        const int r = r0 + tr * 4 + ri;
        float4 gb = *(const float4*)&gBT[r * 4096 + scol];
        float4 z;
        z.x = acc[ri][0] + gb.x;
        z.y = acc[ri][1] + gb.y;
        z.z = acc[ri][2] + gb.z;
        z.w = acc[ri][3] + gb.w;
        *(float4*)&ZT[r * 4096 + scol] = z;
    }
}

// ---------------------------------------------------------------------------
// Sweep scan: given gate preactivations ZT[r][s] (r = g*256+u), compute the
// EXACT c-trajectory per hidden unit via parallel affine scan
//   c[s] = af[s]*c[s-1] + uu[s],  af = sig(f), uu = sig(i)*tanh(g)
// then h[s] = sig(o[s])*tanh(c[s]) -> hTbuf[u][1+s].
// grid 256 (one block per unit), block 256 (16 steps/thread serial +
// Hillis-Steele inclusive scan of affine composites in LDS).
// ---------------------------------------------------------------------------
__global__ __launch_bounds__(256, 1)
void scan_sweep(const float* __restrict__ ZT, float* __restrict__ hTbuf)
{
    const int u = blockIdx.x;
    const int t = threadIdx.x;
    const int s0 = t * 16;

    const float* zi = ZT + (0 * 256 + u) * 4096 + s0;
    const float* zf = ZT + (1 * 256 + u) * 4096 + s0;
    const float* zg = ZT + (2 * 256 + u) * 4096 + s0;
    const float* zo = ZT + (3 * 256 + u) * 4096 + s0;

    float4 iv[4], fv[4], gv[4], ov[4];
    #pragma unroll
    for (int p = 0; p < 4; ++p) {
        iv[p] = *(const float4*)&zi[p * 4];
        fv[p] = *(const float4*)&zf[p * 4];
        gv[p] = *(const float4*)&zg[p * 4];
        ov[p] = *(const float4*)&zo[p * 4];
    }
    float af[16], uu[16];
    const float* ivp = (const float*)iv;
    const float* fvp = (const float*)fv;
    const float* gvp = (const float*)gv;
    float A = 1.f, U = 0.f;
    #pragma unroll
    for (int k = 0; k < 16; ++k) {
        af[k] = sig_(fvp[k]);
        uu[k] = sig_(ivp[k]) * th_(gvp[k]);
        U = af[k] * U + uu[k];
        A = af[k] * A;
    }

    __shared__ float As[256], Us[256];
    As[t] = A; Us[t] = U;
    __syncthreads();
    #pragma unroll
    for (int off = 1; off < 256; off <<= 1) {
        float eA = 1.f, eU = 0.f;
        if (t >= off) { eA = As[t - off]; eU = Us[t - off]; }
        __syncthreads();
        U = A * eU + U;
        A = A * eA;
        As[t] = A; Us[t] = U;
        __syncthreads();
    }
    float c = (t > 0) ? Us[t - 1] : 0.f;  // exclusive prefix -> entry c

    float* hp = hTbuf + u * HSTRIDE + 1 + s0;
    const float* ovp = (const float*)ov;
    #pragma unroll
    for (int k = 0; k < 16; ++k) {
        c = af[k] * c + uu[k];
        hp[k] = sig_(ovp[k]) * th_(c);
    }
}

// ---------------------------------------------------------------------------
// Final linear: out = h[4095] . lin_W + lin_b
// ---------------------------------------------------------------------------
__global__ __launch_bounds__(256)
void out_kernel(const float* __restrict__ hTbuf, const float* __restrict__ linW,
                const float* __restrict__ linb, float* __restrict__ out)
{
    const int tid = threadIdx.x;
    __shared__ float red_lds[4];
    float p = hTbuf[tid * HSTRIDE + 4096] * linW[tid];
    #pragma unroll
    for (int off = 1; off < 64; off <<= 1) p += __shfl_xor(p, off);
    if ((tid & 63) == 0) red_lds[tid >> 6] = p;
    __syncthreads();
    if (tid == 0)
        out[0] = red_lds[0] + red_lds[1] + red_lds[2] + red_lds[3] + linb[0];
}

extern "C" void kernel_launch(void* const* d_in, const int* in_sizes, int n_in,
                              void* d_out, int out_size, void* d_ws, size_t ws_size,
                              hipStream_t stream)
{
    const int*   tok  = (const int*)d_in[0];
    const int*   len  = (const int*)d_in[1];
    const float* emb  = (const float*)d_in[2];
    const float* tWih = (const float*)d_in[3];
    const float* tWhh = (const float*)d_in[4];
    const float* tb   = (const float*)d_in[5];
    const float* iWih = (const float*)d_in[6];
    const float* iWhh = (const float*)d_in[7];
    const float* ib   = (const float*)d_in[8];
    const float* lW   = (const float*)d_in[9];
    const float* lb   = (const float*)d_in[10];
    float* out = (float*)d_out;

    // workspace (floats), ~46 MB total; ZT aliases the dead phase-1 region
    float* emb2   = (float*)d_ws;           // [2000][1024]
    float* hbuf0  = emb2  + 2048000;        // [4096][256] ping   (phase 1)
    float* hbuf1  = hbuf0 + 1048576;        // [4096][256] pong   (phase 1)
    float* cbuf   = hbuf1 + 1048576;        // [4096][256]        (phase 1)
    float* feats  = cbuf  + 1048576;        // [4096][256]
    float* gBT    = feats + 1048576;        // [1024][4096] gate bias, transposed
    float* hTbuf  = gBT   + 4194304;        // [256][HSTRIDE], col0 = 0 pad
    float* ZT     = (float*)d_ws;           // [1024][4096] alias emb2..cbuf (dead)

    // hTbuf: zero (col 0 must be 0 = h[-1]); ws is poisoned 0xAA each call
    hipMemsetAsync(hTbuf, 0, (size_t)256 * HSTRIDE * sizeof(float), stream);

    // ---- phase 1: token LSTM (batch-parallel) ----
    gemm_fused<<<dim3(32, 4), 256, 0, stream>>>(emb, tWih, tb, emb2, 2000, 0,
                                                nullptr, 0, nullptr, nullptr,
                                                nullptr, nullptr, nullptr);
    step0_kernel<<<4096, 256, 0, stream>>>(tok, len, emb2, cbuf, hbuf0, feats);
    for (int t = 1; t < 16; ++t) {
        float* hprev = (t & 1) ? hbuf0 : hbuf1;
        float* hcur  = (t & 1) ? hbuf1 : hbuf0;
        gemm_fused<<<dim3(64, 4), 256, 0, stream>>>(hprev, tWhh, nullptr, nullptr,
                                                    4096, 1, tok, t, emb2, len,
                                                    cbuf, hcur, feats);
    }
    // gBT[r][s] = (feats @ ins_W_ih^T + ins_b) transposed
    gemm_fused<<<dim3(64, 4), 256, 0, stream>>>(feats, iWih, ib, gBT, 4096, 3,
                                                nullptr, 0, nullptr, nullptr,
                                                nullptr, nullptr, nullptr);

    // ---- phase 2: fixed-point sweeps (no cross-block sync anywhere) ----
    // sweep 1: h_old = 0 -> Z = gBT, run scan directly on it
    scan_sweep<<<256, 256, 0, stream>>>(gBT, hTbuf);
    for (int k = 1; k < SWEEPS; ++k) {
        gemm_zT<<<dim3(64, 16), 256, 0, stream>>>(iWhh, hTbuf, gBT, ZT);
        scan_sweep<<<256, 256, 0, stream>>>(ZT, hTbuf);
    }

    out_kernel<<<1, 256, 0, stream>>>(hTbuf, lW, lb, out);
}

// Round 7
// 1632.167 us; speedup vs baseline: 5.7024x; 1.5673x over previous
//
#include <hip/hip_runtime.h>

#define SWEEPS 20
#define HSTRIDE 4112   // hTbuf row stride: 4096 + front pad(1) + slack, %4==0

__device__ __forceinline__ float sig_(float x) { return 1.0f / (1.0f + __expf(-x)); }
__device__ __forceinline__ float th_(float x)  { return 1.0f - 2.0f / (__expf(2.0f * x) + 1.0f); }

// ---------------------------------------------------------------------------
// emb2 build: emb2[v][g*256+j] = sum_k emb[v][k]*tWih[g*256+j][k] + tb
// grid (32, 4), block 256, tile 64v x 64j x 4 gates. (runs once, ~75 us)
// ---------------------------------------------------------------------------
__global__ __launch_bounds__(256, 2)
void gemm_emb2(const float* __restrict__ A, const float* __restrict__ Wt,
               const float* __restrict__ bias, float* __restrict__ Cout, int M)
{
    __shared__ float a_lds[32][64];
    __shared__ float b_lds[4][32][64];
    const int tid = threadIdx.x;
    const int tn = tid & 15;
    const int th = tid >> 4;
    const int m0 = blockIdx.x * 64;
    const int j0 = blockIdx.y * 64;

    float acc[4][4][4];
    #pragma unroll
    for (int g = 0; g < 4; ++g)
        #pragma unroll
        for (int x = 0; x < 4; ++x)
            #pragma unroll
            for (int y = 0; y < 4; ++y) acc[g][x][y] = 0.f;

    float4 abuf[2], bbuf[8];
    auto load_t = [&](int k0) {
        #pragma unroll
        for (int p = 0; p < 2; ++p) {
            int idx = tid + p * 256, ml = idx >> 3, k4 = idx & 7;
            int row = m0 + ml;
            abuf[p] = (row < M) ? *(const float4*)&A[row * 256 + k0 + k4 * 4]
                                : make_float4(0.f, 0.f, 0.f, 0.f);
        }
        #pragma unroll
        for (int p = 0; p < 8; ++p) {
            int idx = tid + p * 256;
            int g = idx >> 9, rem = idx & 511, r = rem >> 3, k4 = rem & 7;
            bbuf[p] = *(const float4*)&Wt[(g * 256 + j0 + r) * 256 + k0 + k4 * 4];
        }
    };
    auto store_t = [&]() {
        #pragma unroll
        for (int p = 0; p < 2; ++p) {
            int idx = tid + p * 256, ml = idx >> 3, k4 = idx & 7;
            a_lds[k4 * 4 + 0][ml] = abuf[p].x;
            a_lds[k4 * 4 + 1][ml] = abuf[p].y;
            a_lds[k4 * 4 + 2][ml] = abuf[p].z;
            a_lds[k4 * 4 + 3][ml] = abuf[p].w;
        }
        #pragma unroll
        for (int p = 0; p < 8; ++p) {
            int idx = tid + p * 256;
            int g = idx >> 9, rem = idx & 511, r = rem >> 3, k4 = rem & 7;
            b_lds[g][k4 * 4 + 0][r] = bbuf[p].x;
            b_lds[g][k4 * 4 + 1][r] = bbuf[p].y;
            b_lds[g][k4 * 4 + 2][r] = bbuf[p].z;
            b_lds[g][k4 * 4 + 3][r] = bbuf[p].w;
        }
    };

    load_t(0); store_t(); __syncthreads();
    for (int c = 0; c < 8; ++c) {
        if (c < 7) load_t((c + 1) * 32);
        #pragma unroll 8
        for (int k = 0; k < 32; ++k) {
            float4 a4 = *(const float4*)&a_lds[k][tn * 4];
            float av[4] = {a4.x, a4.y, a4.z, a4.w};
            #pragma unroll
            for (int g = 0; g < 4; ++g) {
                float4 b4 = *(const float4*)&b_lds[g][k][th * 4];
                float bv[4] = {b4.x, b4.y, b4.z, b4.w};
                #pragma unroll
                for (int hi = 0; hi < 4; ++hi)
                    #pragma unroll
                    for (int ni = 0; ni < 4; ++ni)
                        acc[g][hi][ni] += bv[hi] * av[ni];
            }
        }
        __syncthreads();
        if (c < 7) { store_t(); __syncthreads(); }
    }

    const int colb = j0 + th * 4;
    float4 bs[4];
    #pragma unroll
    for (int g = 0; g < 4; ++g) bs[g] = *(const float4*)&bias[g * 256 + colb];
    #pragma unroll
    for (int ni = 0; ni < 4; ++ni) {
        int row = m0 + tn * 4 + ni;
        if (row < M) {
            #pragma unroll
            for (int g = 0; g < 4; ++g) {
                float4 o;
                o.x = acc[g][0][ni] + bs[g].x;
                o.y = acc[g][1][ni] + bs[g].y;
                o.z = acc[g][2][ni] + bs[g].z;
                o.w = acc[g][3][ni] + bs[g].w;
                *(float4*)&Cout[row * 1024 + g * 256 + colb] = o;
            }
        }
    }
}

// ---------------------------------------------------------------------------
// Token-LSTM step 0 (h0=c0=0 -> pointwise emb2 gather), TRANSPOSED layout.
// grid (64, 16): n-tile 64, u-tile 16. Thread: 1 u x 4 n (float4 writes).
// ---------------------------------------------------------------------------
__global__ __launch_bounds__(256)
void step0T(const int* __restrict__ tok, const int* __restrict__ len,
            const float* __restrict__ emb2, float* __restrict__ cT,
            float* __restrict__ hT0, float* __restrict__ featsT)
{
    const int tid = threadIdx.x;
    const int tn = tid & 15, tu = tid >> 4;
    const int u  = blockIdx.y * 16 + tu;
    const int n0 = blockIdx.x * 64 + tn * 4;
    float h4[4], c4[4];
    #pragma unroll
    for (int j = 0; j < 4; ++j) {
        int n = n0 + j;
        int v = tok[n * 16];
        const float* e = emb2 + v * 1024 + u;
        float ig = e[0], gg = e[512], og = e[768];
        float c = sig_(ig) * th_(gg);
        float h = sig_(og) * th_(c);
        c4[j] = c; h4[j] = h;
        if (len[n] == 1) featsT[u * 4096 + n] = h;
    }
    *(float4*)&cT[u * 4096 + n0]  = make_float4(c4[0], c4[1], c4[2], c4[3]);
    *(float4*)&hT0[u * 4096 + n0] = make_float4(h4[0], h4[1], h4[2], h4[3]);
}

// ---------------------------------------------------------------------------
// Token-LSTM step t (t>=1), fully fused, TRANSPOSED:
//   gates[r][n] = sum_k tWhh[r][k] * hTprev[k][n]  (+ emb2 gather in epilogue)
// r-tile = 16 units x 4 gates: local row rl = i*4+g maps to W row g*256+ub*16+i,
// so each thread's 4 acc rows are the 4 gates of ONE unit -> LSTM pointwise
// (c/h update, feats) lives in the epilogue. grid (64, 16) = 1024 blocks.
// ---------------------------------------------------------------------------
__global__ __launch_bounds__(256, 4)
void stepT(const float* __restrict__ Whh, const float* __restrict__ hTprev,
           const int* __restrict__ tok, int t, const float* __restrict__ emb2,
           const int* __restrict__ len, float* __restrict__ cT,
           float* __restrict__ hTnext, float* __restrict__ featsT)
{
    __shared__ float w_lds[32][68];       // [k][rl], rl = i*4+g
    __shared__ float h_lds[32][68];       // [k][s]
    const int tid = threadIdx.x;
    const int tr = tid & 15;              // unit within tile
    const int ts = tid >> 4;              // n-quad
    const int ub = blockIdx.y;
    const int s0 = blockIdx.x * 64;
    const int u    = ub * 16 + tr;
    const int scol = s0 + ts * 4;

    // prefetch epilogue inputs early (independent of GEMM)
    int vids[4], lens[4];
    #pragma unroll
    for (int j = 0; j < 4; ++j) {
        vids[j] = tok[(scol + j) * 16 + t];
        lens[j] = len[scol + j];
    }
    float4 cold = *(const float4*)&cT[u * 4096 + scol];

    float acc[4][4];                      // [gate][si]
    #pragma unroll
    for (int x = 0; x < 4; ++x)
        #pragma unroll
        for (int y = 0; y < 4; ++y) acc[x][y] = 0.f;

    float4 wbuf[2], hbuf[2];
    auto load_t = [&](int k0) {
        #pragma unroll
        for (int p = 0; p < 2; ++p) {
            int idx = tid + p * 256;
            int rl = idx >> 3, k4 = idx & 7;
            int gi = rl & 3, ii = rl >> 2;
            wbuf[p] = *(const float4*)&Whh[(gi * 256 + ub * 16 + ii) * 256 + k0 + k4 * 4];
            int jj = idx >> 4, s4 = idx & 15;
            hbuf[p] = *(const float4*)&hTprev[(k0 + jj) * 4096 + s0 + s4 * 4];
        }
    };
    auto store_t = [&]() {
        #pragma unroll
        for (int p = 0; p < 2; ++p) {
            int idx = tid + p * 256;
            int rl = idx >> 3, k4 = idx & 7;
            w_lds[k4 * 4 + 0][rl] = wbuf[p].x;
            w_lds[k4 * 4 + 1][rl] = wbuf[p].y;
            w_lds[k4 * 4 + 2][rl] = wbuf[p].z;
            w_lds[k4 * 4 + 3][rl] = wbuf[p].w;
            int jj = idx >> 4, s4 = idx & 15;
            *(float4*)&h_lds[jj][s4 * 4] = hbuf[p];
        }
    };

    load_t(0); store_t(); __syncthreads();
    for (int c = 0; c < 8; ++c) {
        if (c < 7) load_t((c + 1) * 32);
        #pragma unroll 8
        for (int k = 0; k < 32; ++k) {
            float4 wv = *(const float4*)&w_lds[k][tr * 4];  // 4 gates of unit tr
            float4 hv = *(const float4*)&h_lds[k][ts * 4];
            float wa[4] = {wv.x, wv.y, wv.z, wv.w};
            float ha[4] = {hv.x, hv.y, hv.z, hv.w};
            #pragma unroll
            for (int g = 0; g < 4; ++g)
                #pragma unroll
                for (int si = 0; si < 4; ++si)
                    acc[g][si] += wa[g] * ha[si];
        }
        __syncthreads();
        if (c < 7) { store_t(); __syncthreads(); }
    }

    // epilogue: emb2 gather + LSTM update for unit u, 4 seqs
    const float* coldp = (const float*)&cold;
    float c4[4], h4[4];
    #pragma unroll
    for (int j = 0; j < 4; ++j) {
        const float* e = emb2 + vids[j] * 1024 + u;
        float ig = acc[0][j] + e[0];
        float fg = acc[1][j] + e[256];
        float gg = acc[2][j] + e[512];
        float og = acc[3][j] + e[768];
        float cc = sig_(fg) * coldp[j] + sig_(ig) * th_(gg);
        c4[j] = cc;
        h4[j] = sig_(og) * th_(cc);
        if (lens[j] == t + 1) featsT[u * 4096 + scol + j] = h4[j];
    }
    *(float4*)&cT[u * 4096 + scol]     = make_float4(c4[0], c4[1], c4[2], c4[3]);
    *(float4*)&hTnext[u * 4096 + scol] = make_float4(h4[0], h4[1], h4[2], h4[3]);
}

// ---------------------------------------------------------------------------
// Generalized T-GEMM: Out[r][s] = sum_k W[r][k] * X[k*xstride + s] (+ add)
// add: addm (matrix [r][s], stride 4096) if non-null, else bias[r] broadcast.
// Phase-2 use: X = hTbuf (HSTRIDE, front pad -> X[k][s] = h[k][s-1]).
// gBT build:   X = featsT (stride 4096), bias = ins_b.
// grid (64, 16), block 256, tile 64r x 64s, K=256.
// ---------------------------------------------------------------------------
__global__ __launch_bounds__(256, 4)
void gemm_T(const float* __restrict__ W, const float* __restrict__ X, int xstride,
            const float* __restrict__ addm, const float* __restrict__ bias,
            float* __restrict__ Out)
{
    __shared__ float w_lds[32][68];
    __shared__ float h_lds[32][68];
    const int tid = threadIdx.x;
    const int tr = tid & 15;
    const int ts = tid >> 4;
    const int s0 = blockIdx.x * 64;
    const int r0 = blockIdx.y * 64;

    float acc[4][4];
    #pragma unroll
    for (int x = 0; x < 4; ++x)
        #pragma unroll
        for (int y = 0; y < 4; ++y) acc[x][y] = 0.f;

    float4 wbuf[2], hbuf[2];
    auto load_t = [&](int k0) {
        #pragma unroll
        for (int p = 0; p < 2; ++p) {
            int idx = tid + p * 256;
            int r = idx >> 3, k4 = idx & 7;
            wbuf[p] = *(const float4*)&W[(r0 + r) * 256 + k0 + k4 * 4];
            int j = idx >> 4, s4 = idx & 15;
            hbuf[p] = *(const float4*)&X[(k0 + j) * xstride + s0 + s4 * 4];
        }
    };
    auto store_t = [&]() {
        #pragma unroll
        for (int p = 0; p < 2; ++p) {
            int idx = tid + p * 256;
            int r = idx >> 3, k4 = idx & 7;
            w_lds[k4 * 4 + 0][r] = wbuf[p].x;
            w_lds[k4 * 4 + 1][r] = wbuf[p].y;
            w_lds[k4 * 4 + 2][r] = wbuf[p].z;
            w_lds[k4 * 4 + 3][r] = wbuf[p].w;
            int j = idx >> 4, s4 = idx & 15;
            *(float4*)&h_lds[j][s4 * 4] = hbuf[p];
        }
    };

    load_t(0); store_t(); __syncthreads();
    for (int c = 0; c < 8; ++c) {
        if (c < 7) load_t((c + 1) * 32);
        #pragma unroll 8
        for (int k = 0; k < 32; ++k) {
            float4 wv = *(const float4*)&w_lds[k][tr * 4];
            float4 hv = *(const float4*)&h_lds[k][ts * 4];
            float wa[4] = {wv.x, wv.y, wv.z, wv.w};
            float ha[4] = {hv.x, hv.y, hv.z, hv.w};
            #pragma unroll
            for (int ri = 0; ri < 4; ++ri)
                #pragma unroll
                for (int si = 0; si < 4; ++si)
                    acc[ri][si] += wa[ri] * ha[si];
        }
        __syncthreads();
        if (c < 7) { store_t(); __syncthreads(); }
    }

    const int scol = s0 + ts * 4;
    #pragma unroll
    for (int ri = 0; ri < 4; ++ri) {
        const int r = r0 + tr * 4 + ri;
        float4 z;
        if (addm) {
            float4 gb = *(const float4*)&addm[r * 4096 + scol];
            z.x = acc[ri][0] + gb.x; z.y = acc[ri][1] + gb.y;
            z.z = acc[ri][2] + gb.z; z.w = acc[ri][3] + gb.w;
        } else {
            float bb = bias[r];
            z.x = acc[ri][0] + bb; z.y = acc[ri][1] + bb;
            z.z = acc[ri][2] + bb; z.w = acc[ri][3] + bb;
        }
        *(float4*)&Out[r * 4096 + scol] = z;
    }
}

// ---------------------------------------------------------------------------
// Sweep scan: exact per-unit affine scan of c given gate preactivations ZT,
// then h = sig(o)*tanh(c) -> hTbuf[u][1+s]. grid 256, block 256.
// ---------------------------------------------------------------------------
__global__ __launch_bounds__(256, 1)
void scan_sweep(const float* __restrict__ ZT, float* __restrict__ hTbuf)
{
    const int u = blockIdx.x;
    const int t = threadIdx.x;
    const int s0 = t * 16;

    const float* zi = ZT + (0 * 256 + u) * 4096 + s0;
    const float* zf = ZT + (1 * 256 + u) * 4096 + s0;
    const float* zg = ZT + (2 * 256 + u) * 4096 + s0;
    const float* zo = ZT + (3 * 256 + u) * 4096 + s0;

    float4 iv[4], fv[4], gv[4], ov[4];
    #pragma unroll
    for (int p = 0; p < 4; ++p) {
        iv[p] = *(const float4*)&zi[p * 4];
        fv[p] = *(const float4*)&zf[p * 4];
        gv[p] = *(const float4*)&zg[p * 4];
        ov[p] = *(const float4*)&zo[p * 4];
    }
    float af[16], uu[16];
    const float* ivp = (const float*)iv;
    const float* fvp = (const float*)fv;
    const float* gvp = (const float*)gv;
    float A = 1.f, U = 0.f;
    #pragma unroll
    for (int k = 0; k < 16; ++k) {
        af[k] = sig_(fvp[k]);
        uu[k] = sig_(ivp[k]) * th_(gvp[k]);
        U = af[k] * U + uu[k];
        A = af[k] * A;
    }

    __shared__ float As[256], Us[256];
    As[t] = A; Us[t] = U;
    __syncthreads();
    #pragma unroll
    for (int off = 1; off < 256; off <<= 1) {
        float eA = 1.f, eU = 0.f;
        if (t >= off) { eA = As[t - off]; eU = Us[t - off]; }
        __syncthreads();
        U = A * eU + U;
        A = A * eA;
        As[t] = A; Us[t] = U;
        __syncthreads();
    }
    float c = (t > 0) ? Us[t - 1] : 0.f;  // exclusive prefix -> entry c

    float* hp = hTbuf + u * HSTRIDE + 1 + s0;
    const float* ovp = (const float*)ov;
    #pragma unroll
    for (int k = 0; k < 16; ++k) {
        c = af[k] * c + uu[k];
        hp[k] = sig_(ovp[k]) * th_(c);
    }
}

// ---------------------------------------------------------------------------
// Final linear: out = h[4095] . lin_W + lin_b
// ---------------------------------------------------------------------------
__global__ __launch_bounds__(256)
void out_kernel(const float* __restrict__ hTbuf, const float* __restrict__ linW,
                const float* __restrict__ linb, float* __restrict__ out)
{
    const int tid = threadIdx.x;
    __shared__ float red_lds[4];
    float p = hTbuf[tid * HSTRIDE + 4096] * linW[tid];
    #pragma unroll
    for (int off = 1; off < 64; off <<= 1) p += __shfl_xor(p, off);
    if ((tid & 63) == 0) red_lds[tid >> 6] = p;
    __syncthreads();
    if (tid == 0)
        out[0] = red_lds[0] + red_lds[1] + red_lds[2] + red_lds[3] + linb[0];
}

extern "C" void kernel_launch(void* const* d_in, const int* in_sizes, int n_in,
                              void* d_out, int out_size, void* d_ws, size_t ws_size,
                              hipStream_t stream)
{
    const int*   tok  = (const int*)d_in[0];
    const int*   len  = (const int*)d_in[1];
    const float* emb  = (const float*)d_in[2];
    const float* tWih = (const float*)d_in[3];
    const float* tWhh = (const float*)d_in[4];
    const float* tb   = (const float*)d_in[5];
    const float* iWih = (const float*)d_in[6];
    const float* iWhh = (const float*)d_in[7];
    const float* ib   = (const float*)d_in[8];
    const float* lW   = (const float*)d_in[9];
    const float* lb   = (const float*)d_in[10];
    float* out = (float*)d_out;

    // workspace (floats), ~46 MB; ZT (phase 2) aliases hT0..featsT (dead)
    float* emb2   = (float*)d_ws;           // [2000][1024]   8 MB
    float* hT0    = emb2   + 2048000;       // [256][4096]    4 MB
    float* hT1    = hT0    + 1048576;       // [256][4096]
    float* cT     = hT1    + 1048576;       // [256][4096]
    float* featsT = cT     + 1048576;       // [256][4096]
    float* gBT    = featsT + 1048576;       // [1024][4096]  16 MB
    float* hTbuf  = gBT    + 4194304;       // [256][HSTRIDE], col0 = 0 pad
    float* ZT     = hT0;                    // [1024][4096] alias (phase 2 only)

    // hTbuf col 0 must be 0 (h[-1]); full zero is ~1 us
    hipMemsetAsync(hTbuf, 0, (size_t)256 * HSTRIDE * sizeof(float), stream);

    // ---- phase 1: token LSTM, transposed batch-parallel ----
    gemm_emb2<<<dim3(32, 4), 256, 0, stream>>>(emb, tWih, tb, emb2, 2000);
    step0T<<<dim3(64, 16), 256, 0, stream>>>(tok, len, emb2, cT, hT0, featsT);
    for (int t = 1; t < 16; ++t) {
        float* hprev = (t & 1) ? hT0 : hT1;
        float* hcur  = (t & 1) ? hT1 : hT0;
        stepT<<<dim3(64, 16), 256, 0, stream>>>(tWhh, hprev, tok, t, emb2, len,
                                                cT, hcur, featsT);
    }
    // gBT[r][s] = ins_W_ih . featsT + ins_b
    gemm_T<<<dim3(64, 16), 256, 0, stream>>>(iWih, featsT, 4096, nullptr, ib, gBT);

    // ---- phase 2: fixed-point sweeps (no cross-block sync) ----
    scan_sweep<<<256, 256, 0, stream>>>(gBT, hTbuf);    // sweep 1: h_old = 0
    for (int k = 1; k < SWEEPS; ++k) {
        gemm_T<<<dim3(64, 16), 256, 0, stream>>>(iWhh, hTbuf, HSTRIDE, gBT,
                                                 nullptr, ZT);
        scan_sweep<<<256, 256, 0, stream>>>(ZT, hTbuf);
    }

    out_kernel<<<1, 256, 0, stream>>>(hTbuf, lW, lb, out);
}

// Round 8
// 1441.317 us; speedup vs baseline: 6.4574x; 1.1324x over previous
//
#include <hip/hip_runtime.h>

#define SWEEPS 16
#define HSTRIDE 4112   // hTbuf row stride: 4096 + front pad(1) + slack, %4==0

__device__ __forceinline__ float sig_(float x) { return 1.0f / (1.0f + __expf(-x)); }
__device__ __forceinline__ float th_(float x)  { return 1.0f - 2.0f / (__expf(2.0f * x) + 1.0f); }

// ---------------------------------------------------------------------------
// emb2 build: emb2[v][j] = sum_k emb[v][k]*tWih[j][k] + tb[j]   (j = 0..1023)
// grid (32, 16), block 256, tile 64v x 64j, 4x4 microtile. 512 blocks.
// ---------------------------------------------------------------------------
__global__ __launch_bounds__(256, 2)
void gemm_emb2(const float* __restrict__ A, const float* __restrict__ Wt,
               const float* __restrict__ bias, float* __restrict__ Cout, int M)
{
    __shared__ float a_lds[32][68];       // [k][m]
    __shared__ float b_lds[32][68];       // [k][j]
    const int tid = threadIdx.x;
    const int tn = tid & 15;
    const int th = tid >> 4;
    const int m0 = blockIdx.x * 64;
    const int j0 = blockIdx.y * 64;

    float acc[4][4];
    #pragma unroll
    for (int x = 0; x < 4; ++x)
        #pragma unroll
        for (int y = 0; y < 4; ++y) acc[x][y] = 0.f;

    float4 abuf[2], bbuf[2];
    auto load_t = [&](int k0) {
        #pragma unroll
        for (int p = 0; p < 2; ++p) {
            int idx = tid + p * 256, ml = idx >> 3, k4 = idx & 7;
            int row = m0 + ml;
            abuf[p] = (row < M) ? *(const float4*)&A[row * 256 + k0 + k4 * 4]
                                : make_float4(0.f, 0.f, 0.f, 0.f);
            bbuf[p] = *(const float4*)&Wt[(j0 + ml) * 256 + k0 + k4 * 4];
        }
    };
    auto store_t = [&]() {
        #pragma unroll
        for (int p = 0; p < 2; ++p) {
            int idx = tid + p * 256, ml = idx >> 3, k4 = idx & 7;
            a_lds[k4 * 4 + 0][ml] = abuf[p].x;
            a_lds[k4 * 4 + 1][ml] = abuf[p].y;
            a_lds[k4 * 4 + 2][ml] = abuf[p].z;
            a_lds[k4 * 4 + 3][ml] = abuf[p].w;
            b_lds[k4 * 4 + 0][ml] = bbuf[p].x;
            b_lds[k4 * 4 + 1][ml] = bbuf[p].y;
            b_lds[k4 * 4 + 2][ml] = bbuf[p].z;
            b_lds[k4 * 4 + 3][ml] = bbuf[p].w;
        }
    };

    load_t(0); store_t(); __syncthreads();
    for (int c = 0; c < 8; ++c) {
        if (c < 7) load_t((c + 1) * 32);
        #pragma unroll 8
        for (int k = 0; k < 32; ++k) {
            float4 a4 = *(const float4*)&a_lds[k][tn * 4];
            float4 b4 = *(const float4*)&b_lds[k][th * 4];
            float av[4] = {a4.x, a4.y, a4.z, a4.w};
            float bv[4] = {b4.x, b4.y, b4.z, b4.w};
            #pragma unroll
            for (int mi = 0; mi < 4; ++mi)
                #pragma unroll
                for (int ji = 0; ji < 4; ++ji)
                    acc[mi][ji] += av[mi] * bv[ji];
        }
        __syncthreads();
        if (c < 7) { store_t(); __syncthreads(); }
    }

    const int jcol = j0 + th * 4;
    float4 bs = *(const float4*)&bias[jcol];
    #pragma unroll
    for (int mi = 0; mi < 4; ++mi) {
        int row = m0 + tn * 4 + mi;
        if (row < M) {
            float4 o;
            o.x = acc[mi][0] + bs.x;
            o.y = acc[mi][1] + bs.y;
            o.z = acc[mi][2] + bs.z;
            o.w = acc[mi][3] + bs.w;
            *(float4*)&Cout[row * 1024 + jcol] = o;
        }
    }
}

// ---------------------------------------------------------------------------
// Token-LSTM step 0 (h0=c0=0 -> pointwise emb2 gather), TRANSPOSED layout.
// ---------------------------------------------------------------------------
__global__ __launch_bounds__(256)
void step0T(const int* __restrict__ tok, const int* __restrict__ len,
            const float* __restrict__ emb2, float* __restrict__ cT,
            float* __restrict__ hT0, float* __restrict__ featsT)
{
    const int tid = threadIdx.x;
    const int tn = tid & 15, tu = tid >> 4;
    const int u  = blockIdx.y * 16 + tu;
    const int n0 = blockIdx.x * 64 + tn * 4;
    float h4[4], c4[4];
    #pragma unroll
    for (int j = 0; j < 4; ++j) {
        int n = n0 + j;
        int v = tok[n * 16];
        const float* e = emb2 + v * 1024 + u;
        float ig = e[0], gg = e[512], og = e[768];
        float c = sig_(ig) * th_(gg);
        float h = sig_(og) * th_(c);
        c4[j] = c; h4[j] = h;
        if (len[n] == 1) featsT[u * 4096 + n] = h;
    }
    *(float4*)&cT[u * 4096 + n0]  = make_float4(c4[0], c4[1], c4[2], c4[3]);
    *(float4*)&hT0[u * 4096 + n0] = make_float4(h4[0], h4[1], h4[2], h4[3]);
}

// ---------------------------------------------------------------------------
// Token-LSTM step t (t>=1), fused, TRANSPOSED, 128r x 64s tile (8x4 micro).
// r-local rl = i*4+g (i = unit-local 0..31): thread (tr) owns rl = tr*8..+8
// = 2 units x 4 gates -> full LSTM pointwise in epilogue. grid (64, 8).
// ---------------------------------------------------------------------------
__global__ __launch_bounds__(256, 2)
void stepT(const float* __restrict__ Whh, const float* __restrict__ hTprev,
           const int* __restrict__ tok, int t, const float* __restrict__ emb2,
           const int* __restrict__ len, float* __restrict__ cT,
           float* __restrict__ hTnext, float* __restrict__ featsT)
{
    __shared__ float w_lds[32][132];      // [k][rl]
    __shared__ float h_lds[32][68];       // [k][s]
    const int tid = threadIdx.x;
    const int tr = tid & 15;              // r-octet
    const int ts = tid >> 4;              // s-quad
    const int ub = blockIdx.y;            // unit-tile (32 units)
    const int s0 = blockIdx.x * 64;
    const int scol = s0 + ts * 4;

    // prefetch epilogue inputs early (independent of GEMM)
    int vids[4], lens[4];
    #pragma unroll
    for (int j = 0; j < 4; ++j) {
        vids[j] = tok[(scol + j) * 16 + t];
        lens[j] = len[scol + j];
    }

    float acc[8][4];
    #pragma unroll
    for (int x = 0; x < 8; ++x)
        #pragma unroll
        for (int y = 0; y < 4; ++y) acc[x][y] = 0.f;

    float4 wbuf[4], hbuf[2];
    auto load_t = [&](int k0) {
        #pragma unroll
        for (int p = 0; p < 4; ++p) {
            int idx = tid + p * 256;      // 0..1023
            int rl = idx >> 3, k4 = idx & 7;
            int gi = rl & 3, ii = rl >> 2;
            wbuf[p] = *(const float4*)&Whh[(gi * 256 + ub * 32 + ii) * 256 + k0 + k4 * 4];
        }
        #pragma unroll
        for (int p = 0; p < 2; ++p) {
            int idx = tid + p * 256;      // 0..511
            int jj = idx >> 4, s4 = idx & 15;
            hbuf[p] = *(const float4*)&hTprev[(k0 + jj) * 4096 + s0 + s4 * 4];
        }
    };
    auto store_t = [&]() {
        #pragma unroll
        for (int p = 0; p < 4; ++p) {
            int idx = tid + p * 256;
            int rl = idx >> 3, k4 = idx & 7;
            w_lds[k4 * 4 + 0][rl] = wbuf[p].x;
            w_lds[k4 * 4 + 1][rl] = wbuf[p].y;
            w_lds[k4 * 4 + 2][rl] = wbuf[p].z;
            w_lds[k4 * 4 + 3][rl] = wbuf[p].w;
        }
        #pragma unroll
        for (int p = 0; p < 2; ++p) {
            int idx = tid + p * 256;
            int jj = idx >> 4, s4 = idx & 15;
            *(float4*)&h_lds[jj][s4 * 4] = hbuf[p];
        }
    };

    load_t(0); store_t(); __syncthreads();
    for (int c = 0; c < 8; ++c) {
        if (c < 7) load_t((c + 1) * 32);
        #pragma unroll 4
        for (int k = 0; k < 32; ++k) {
            float4 w0 = *(const float4*)&w_lds[k][tr * 8];
            float4 w1 = *(const float4*)&w_lds[k][tr * 8 + 4];
            float4 hv = *(const float4*)&h_lds[k][ts * 4];
            float wa[8] = {w0.x, w0.y, w0.z, w0.w, w1.x, w1.y, w1.z, w1.w};
            float ha[4] = {hv.x, hv.y, hv.z, hv.w};
            #pragma unroll
            for (int ri = 0; ri < 8; ++ri)
                #pragma unroll
                for (int si = 0; si < 4; ++si)
                    acc[ri][si] += wa[ri] * ha[si];
        }
        __syncthreads();
        if (c < 7) { store_t(); __syncthreads(); }
    }

    // epilogue: 2 units x 4 seqs LSTM update
    #pragma unroll
    for (int half = 0; half < 2; ++half) {
        const int u = ub * 32 + tr * 2 + half;
        float4 cold = *(const float4*)&cT[u * 4096 + scol];
        const float* coldp = (const float*)&cold;
        float c4[4], h4[4];
        #pragma unroll
        for (int j = 0; j < 4; ++j) {
            const float* e = emb2 + vids[j] * 1024 + u;
            float ig = acc[half * 4 + 0][j] + e[0];
            float fg = acc[half * 4 + 1][j] + e[256];
            float gg = acc[half * 4 + 2][j] + e[512];
            float og = acc[half * 4 + 3][j] + e[768];
            float cc = sig_(fg) * coldp[j] + sig_(ig) * th_(gg);
            c4[j] = cc;
            h4[j] = sig_(og) * th_(cc);
            if (lens[j] == t + 1) featsT[u * 4096 + scol + j] = h4[j];
        }
        *(float4*)&cT[u * 4096 + scol]     = make_float4(c4[0], c4[1], c4[2], c4[3]);
        *(float4*)&hTnext[u * 4096 + scol] = make_float4(h4[0], h4[1], h4[2], h4[3]);
    }
}

// ---------------------------------------------------------------------------
// T-GEMM 128r x 64s (8x4 micro): Out[r][s] = sum_k W[r][k]*X[k*xstride+s]
// + addm[r][s] (if non-null) else + bias[r]. grid (64, 8), block 256.
// Phase-2: X = hTbuf (HSTRIDE, front pad -> X[k][s] = h[k][s-1]).
// ---------------------------------------------------------------------------
__global__ __launch_bounds__(256, 2)
void gemm_T(const float* __restrict__ W, const float* __restrict__ X, int xstride,
            const float* __restrict__ addm, const float* __restrict__ bias,
            float* __restrict__ Out)
{
    __shared__ float w_lds[32][132];
    __shared__ float h_lds[32][68];
    const int tid = threadIdx.x;
    const int tr = tid & 15;
    const int ts = tid >> 4;
    const int s0 = blockIdx.x * 64;
    const int r0 = blockIdx.y * 128;

    float acc[8][4];
    #pragma unroll
    for (int x = 0; x < 8; ++x)
        #pragma unroll
        for (int y = 0; y < 4; ++y) acc[x][y] = 0.f;

    float4 wbuf[4], hbuf[2];
    auto load_t = [&](int k0) {
        #pragma unroll
        for (int p = 0; p < 4; ++p) {
            int idx = tid + p * 256;
            int r = idx >> 3, k4 = idx & 7;
            wbuf[p] = *(const float4*)&W[(r0 + r) * 256 + k0 + k4 * 4];
        }
        #pragma unroll
        for (int p = 0; p < 2; ++p) {
            int idx = tid + p * 256;
            int jj = idx >> 4, s4 = idx & 15;
            hbuf[p] = *(const float4*)&X[(k0 + jj) * xstride + s0 + s4 * 4];
        }
    };
    auto store_t = [&]() {
        #pragma unroll
        for (int p = 0; p < 4; ++p) {
            int idx = tid + p * 256;
            int r = idx >> 3, k4 = idx & 7;
            w_lds[k4 * 4 + 0][r] = wbuf[p].x;
            w_lds[k4 * 4 + 1][r] = wbuf[p].y;
            w_lds[k4 * 4 + 2][r] = wbuf[p].z;
            w_lds[k4 * 4 + 3][r] = wbuf[p].w;
        }
        #pragma unroll
        for (int p = 0; p < 2; ++p) {
            int idx = tid + p * 256;
            int jj = idx >> 4, s4 = idx & 15;
            *(float4*)&h_lds[jj][s4 * 4] = hbuf[p];
        }
    };

    load_t(0); store_t(); __syncthreads();
    for (int c = 0; c < 8; ++c) {
        if (c < 7) load_t((c + 1) * 32);
        #pragma unroll 4
        for (int k = 0; k < 32; ++k) {
            float4 w0 = *(const float4*)&w_lds[k][tr * 8];
            float4 w1 = *(const float4*)&w_lds[k][tr * 8 + 4];
            float4 hv = *(const float4*)&h_lds[k][ts * 4];
            float wa[8] = {w0.x, w0.y, w0.z, w0.w, w1.x, w1.y, w1.z, w1.w};
            float ha[4] = {hv.x, hv.y, hv.z, hv.w};
            #pragma unroll
            for (int ri = 0; ri < 8; ++ri)
                #pragma unroll
                for (int si = 0; si < 4; ++si)
                    acc[ri][si] += wa[ri] * ha[si];
        }
        __syncthreads();
        if (c < 7) { store_t(); __syncthreads(); }
    }

    const int scol = s0 + ts * 4;
    #pragma unroll
    for (int ri = 0; ri < 8; ++ri) {
        const int r = r0 + tr * 8 + ri;
        float4 z;
        if (addm) {
            float4 gb = *(const float4*)&addm[r * 4096 + scol];
            z.x = acc[ri][0] + gb.x; z.y = acc[ri][1] + gb.y;
            z.z = acc[ri][2] + gb.z; z.w = acc[ri][3] + gb.w;
        } else {
            float bb = bias[r];
            z.x = acc[ri][0] + bb; z.y = acc[ri][1] + bb;
            z.z = acc[ri][2] + bb; z.w = acc[ri][3] + bb;
        }
        *(float4*)&Out[r * 4096 + scol] = z;
    }
}

// ---------------------------------------------------------------------------
// Sweep scan: exact per-unit affine scan of c given gate preactivations ZT,
// then h = sig(o)*tanh(c) -> hTbuf[u][1+s]. grid 256, block 256.
// ---------------------------------------------------------------------------
__global__ __launch_bounds__(256, 1)
void scan_sweep(const float* __restrict__ ZT, float* __restrict__ hTbuf)
{
    const int u = blockIdx.x;
    const int t = threadIdx.x;
    const int s0 = t * 16;

    const float* zi = ZT + (0 * 256 + u) * 4096 + s0;
    const float* zf = ZT + (1 * 256 + u) * 4096 + s0;
    const float* zg = ZT + (2 * 256 + u) * 4096 + s0;
    const float* zo = ZT + (3 * 256 + u) * 4096 + s0;

    float4 iv[4], fv[4], gv[4], ov[4];
    #pragma unroll
    for (int p = 0; p < 4; ++p) {
        iv[p] = *(const float4*)&zi[p * 4];
        fv[p] = *(const float4*)&zf[p * 4];
        gv[p] = *(const float4*)&zg[p * 4];
        ov[p] = *(const float4*)&zo[p * 4];
    }
    float af[16], uu[16];
    const float* ivp = (const float*)iv;
    const float* fvp = (const float*)fv;
    const float* gvp = (const float*)gv;
    float A = 1.f, U = 0.f;
    #pragma unroll
    for (int k = 0; k < 16; ++k) {
        af[k] = sig_(fvp[k]);
        uu[k] = sig_(ivp[k]) * th_(gvp[k]);
        U = af[k] * U + uu[k];
        A = af[k] * A;
    }

    __shared__ float As[256], Us[256];
    As[t] = A; Us[t] = U;
    __syncthreads();
    #pragma unroll
    for (int off = 1; off < 256; off <<= 1) {
        float eA = 1.f, eU = 0.f;
        if (t >= off) { eA = As[t - off]; eU = Us[t - off]; }
        __syncthreads();
        U = A * eU + U;
        A = A * eA;
        As[t] = A; Us[t] = U;
        __syncthreads();
    }
    float c = (t > 0) ? Us[t - 1] : 0.f;  // exclusive prefix -> entry c

    float* hp = hTbuf + u * HSTRIDE + 1 + s0;
    const float* ovp = (const float*)ov;
    #pragma unroll
    for (int k = 0; k < 16; ++k) {
        c = af[k] * c + uu[k];
        hp[k] = sig_(ovp[k]) * th_(c);
    }
}

// ---------------------------------------------------------------------------
// Final linear: out = h[4095] . lin_W + lin_b
// ---------------------------------------------------------------------------
__global__ __launch_bounds__(256)
void out_kernel(const float* __restrict__ hTbuf, const float* __restrict__ linW,
                const float* __restrict__ linb, float* __restrict__ out)
{
    const int tid = threadIdx.x;
    __shared__ float red_lds[4];
    float p = hTbuf[tid * HSTRIDE + 4096] * linW[tid];
    #pragma unroll
    for (int off = 1; off < 64; off <<= 1) p += __shfl_xor(p, off);
    if ((tid & 63) == 0) red_lds[tid >> 6] = p;
    __syncthreads();
    if (tid == 0)
        out[0] = red_lds[0] + red_lds[1] + red_lds[2] + red_lds[3] + linb[0];
}

extern "C" void kernel_launch(void* const* d_in, const int* in_sizes, int n_in,
                              void* d_out, int out_size, void* d_ws, size_t ws_size,
                              hipStream_t stream)
{
    const int*   tok  = (const int*)d_in[0];
    const int*   len  = (const int*)d_in[1];
    const float* emb  = (const float*)d_in[2];
    const float* tWih = (const float*)d_in[3];
    const float* tWhh = (const float*)d_in[4];
    const float* tb   = (const float*)d_in[5];
    const float* iWih = (const float*)d_in[6];
    const float* iWhh = (const float*)d_in[7];
    const float* ib   = (const float*)d_in[8];
    const float* lW   = (const float*)d_in[9];
    const float* lb   = (const float*)d_in[10];
    float* out = (float*)d_out;

    // workspace (floats), ~44 MB; ZT (phase 2) aliases hT0..featsT (dead)
    float* emb2   = (float*)d_ws;           // [2000][1024]   8 MB
    float* hT0    = emb2   + 2048000;       // [256][4096]    4 MB
    float* hT1    = hT0    + 1048576;       // [256][4096]
    float* cT     = hT1    + 1048576;       // [256][4096]
    float* featsT = cT     + 1048576;       // [256][4096]
    float* gBT    = featsT + 1048576;       // [1024][4096]  16 MB
    float* hTbuf  = gBT    + 4194304;       // [256][HSTRIDE], col0 = 0 pad
    float* ZT     = hT0;                    // [1024][4096] alias (phase 2 only)

    // hTbuf col 0 must be 0 (h[-1])
    hipMemsetAsync(hTbuf, 0, (size_t)256 * HSTRIDE * sizeof(float), stream);

    // ---- phase 1: token LSTM, transposed batch-parallel ----
    gemm_emb2<<<dim3(32, 16), 256, 0, stream>>>(emb, tWih, tb, emb2, 2000);
    step0T<<<dim3(64, 16), 256, 0, stream>>>(tok, len, emb2, cT, hT0, featsT);
    for (int t = 1; t < 16; ++t) {
        float* hprev = (t & 1) ? hT0 : hT1;
        float* hcur  = (t & 1) ? hT1 : hT0;
        stepT<<<dim3(64, 8), 256, 0, stream>>>(tWhh, hprev, tok, t, emb2, len,
                                               cT, hcur, featsT);
    }
    // gBT[r][s] = ins_W_ih . featsT + ins_b
    gemm_T<<<dim3(64, 8), 256, 0, stream>>>(iWih, featsT, 4096, nullptr, ib, gBT);

    // ---- phase 2: fixed-point sweeps (no cross-block sync) ----
    scan_sweep<<<256, 256, 0, stream>>>(gBT, hTbuf);    // sweep 1: h_old = 0
    for (int k = 1; k < SWEEPS; ++k) {
        gemm_T<<<dim3(64, 8), 256, 0, stream>>>(iWhh, hTbuf, HSTRIDE, gBT,
                                                nullptr, ZT);
        scan_sweep<<<256, 256, 0, stream>>>(ZT, hTbuf);
    }

    out_kernel<<<1, 256, 0, stream>>>(hTbuf, lW, lb, out);
}

// Round 9
// 1235.471 us; speedup vs baseline: 7.5333x; 1.1666x over previous
//
#include <hip/hip_runtime.h>

#define SWEEPS 13
#define HSTRIDE 4112   // hTbuf row stride: 4096 + front pad(1) + slack, %4==0

__device__ __forceinline__ float sig_(float x) { return 1.0f / (1.0f + __expf(-x)); }
__device__ __forceinline__ float th_(float x)  { return 1.0f - 2.0f / (__expf(2.0f * x) + 1.0f); }

// ---------------------------------------------------------------------------
// emb2 build: emb2[v][j] = sum_k emb[v][k]*tWih[j][k] + tb[j]   (j = 0..1023)
// grid (32, 16), block 256, tile 64v x 64j, 4x4 microtile. 512 blocks.
// ---------------------------------------------------------------------------
__global__ __launch_bounds__(256, 2)
void gemm_emb2(const float* __restrict__ A, const float* __restrict__ Wt,
               const float* __restrict__ bias, float* __restrict__ Cout, int M)
{
    __shared__ float a_lds[32][68];
    __shared__ float b_lds[32][68];
    const int tid = threadIdx.x;
    const int tn = tid & 15;
    const int th = tid >> 4;
    const int m0 = blockIdx.x * 64;
    const int j0 = blockIdx.y * 64;

    float acc[4][4];
    #pragma unroll
    for (int x = 0; x < 4; ++x)
        #pragma unroll
        for (int y = 0; y < 4; ++y) acc[x][y] = 0.f;

    float4 abuf[2], bbuf[2];
    auto load_t = [&](int k0) {
        #pragma unroll
        for (int p = 0; p < 2; ++p) {
            int idx = tid + p * 256, ml = idx >> 3, k4 = idx & 7;
            int row = m0 + ml;
            abuf[p] = (row < M) ? *(const float4*)&A[row * 256 + k0 + k4 * 4]
                                : make_float4(0.f, 0.f, 0.f, 0.f);
            bbuf[p] = *(const float4*)&Wt[(j0 + ml) * 256 + k0 + k4 * 4];
        }
    };
    auto store_t = [&]() {
        #pragma unroll
        for (int p = 0; p < 2; ++p) {
            int idx = tid + p * 256, ml = idx >> 3, k4 = idx & 7;
            a_lds[k4 * 4 + 0][ml] = abuf[p].x;
            a_lds[k4 * 4 + 1][ml] = abuf[p].y;
            a_lds[k4 * 4 + 2][ml] = abuf[p].z;
            a_lds[k4 * 4 + 3][ml] = abuf[p].w;
            b_lds[k4 * 4 + 0][ml] = bbuf[p].x;
            b_lds[k4 * 4 + 1][ml] = bbuf[p].y;
            b_lds[k4 * 4 + 2][ml] = bbuf[p].z;
            b_lds[k4 * 4 + 3][ml] = bbuf[p].w;
        }
    };

    load_t(0); store_t(); __syncthreads();
    for (int c = 0; c < 8; ++c) {
        if (c < 7) load_t((c + 1) * 32);
        #pragma unroll 8
        for (int k = 0; k < 32; ++k) {
            float4 a4 = *(const float4*)&a_lds[k][tn * 4];
            float4 b4 = *(const float4*)&b_lds[k][th * 4];
            float av[4] = {a4.x, a4.y, a4.z, a4.w};
            float bv[4] = {b4.x, b4.y, b4.z, b4.w};
            #pragma unroll
            for (int mi = 0; mi < 4; ++mi)
                #pragma unroll
                for (int ji = 0; ji < 4; ++ji)
                    acc[mi][ji] += av[mi] * bv[ji];
        }
        __syncthreads();
        if (c < 7) { store_t(); __syncthreads(); }
    }

    const int jcol = j0 + th * 4;
    float4 bs = *(const float4*)&bias[jcol];
    #pragma unroll
    for (int mi = 0; mi < 4; ++mi) {
        int row = m0 + tn * 4 + mi;
        if (row < M) {
            float4 o;
            o.x = acc[mi][0] + bs.x;
            o.y = acc[mi][1] + bs.y;
            o.z = acc[mi][2] + bs.z;
            o.w = acc[mi][3] + bs.w;
            *(float4*)&Cout[row * 1024 + jcol] = o;
        }
    }
}

// ---------------------------------------------------------------------------
// Counting sort of sequences by length, DESCENDING. One block.
// perm[p] = original n of sorted slot p; actcnt[t] = #{n : len[n] > t},
// t = 0..16 (actcnt[16] = 0). Slot p active at step t  <=>  p < actcnt[t];
// len == t+1  <=>  actcnt[t+1] <= p < actcnt[t].
// ---------------------------------------------------------------------------
__global__ __launch_bounds__(256)
void sortlen(const int* __restrict__ len, int* __restrict__ perm,
             int* __restrict__ actcnt)
{
    __shared__ int cnt[17], off[17];
    const int tid = threadIdx.x;
    if (tid < 17) cnt[tid] = 0;
    __syncthreads();
    for (int n = tid; n < 4096; n += 256) atomicAdd(&cnt[len[n]], 1);
    __syncthreads();
    if (tid == 0) {
        int run = 0;
        for (int L = 16; L >= 1; --L) { off[L] = run; run += cnt[L]; }
        actcnt[16] = 0;
        for (int t = 1; t < 16; ++t) actcnt[t] = off[t];
        actcnt[0] = 4096;
    }
    __syncthreads();
    for (int n = tid; n < 4096; n += 256) {
        int pos = atomicAdd(&off[len[n]], 1);
        perm[pos] = n;
    }
}

// ---------------------------------------------------------------------------
// Token-LSTM step 0 (h0=c0=0 -> pointwise emb2 gather), TRANSPOSED + sorted.
// Slot p holds sequence perm[p]; h/c stored at slot, feats at original n.
// ---------------------------------------------------------------------------
__global__ __launch_bounds__(256)
void step0T(const int* __restrict__ tok, const int* __restrict__ perm,
            const int* __restrict__ actcnt, const float* __restrict__ emb2,
            float* __restrict__ cT, float* __restrict__ hT0,
            float* __restrict__ featsT)
{
    const int tid = threadIdx.x;
    const int tn = tid & 15, tu = tid >> 4;
    const int u  = blockIdx.y * 16 + tu;
    const int n0 = blockIdx.x * 64 + tn * 4;
    const int a1 = actcnt[1];
    int4 pn = *(const int4*)&perm[n0];
    const int pns[4] = {pn.x, pn.y, pn.z, pn.w};
    float h4[4], c4[4];
    #pragma unroll
    for (int j = 0; j < 4; ++j) {
        int v = tok[pns[j] * 16];
        const float* e = emb2 + v * 1024 + u;
        float ig = e[0], gg = e[512], og = e[768];
        float c = sig_(ig) * th_(gg);
        float h = sig_(og) * th_(c);
        c4[j] = c; h4[j] = h;
        if (n0 + j >= a1) featsT[u * 4096 + pns[j]] = h;   // len == 1
    }
    *(float4*)&cT[u * 4096 + n0]  = make_float4(c4[0], c4[1], c4[2], c4[3]);
    *(float4*)&hT0[u * 4096 + n0] = make_float4(h4[0], h4[1], h4[2], h4[3]);
}

// ---------------------------------------------------------------------------
// Token-LSTM step t (t>=1), fused, TRANSPOSED, sorted, 128r x 64s (8x4).
// Early-exit: blocks with s0 >= actcnt[t] return (length-sorted slots).
// w-LDS skew: phys col = rl + 4*(rl>>5) -> read banks 2-way max (free).
// Double-buffered LDS chunks: ONE barrier per chunk.
// ---------------------------------------------------------------------------
__global__ __launch_bounds__(256, 2)
void stepT(const float* __restrict__ Whh, const float* __restrict__ hTprev,
           const int* __restrict__ tok, int t, const float* __restrict__ emb2,
           const int* __restrict__ perm, const int* __restrict__ actcnt,
           float* __restrict__ cT, float* __restrict__ hTnext,
           float* __restrict__ featsT)
{
    const int s0 = blockIdx.x * 64;
    const int a_t  = actcnt[t];
    if (s0 >= a_t) return;                // inactive tile: all lengths <= t
    const int a_t1 = actcnt[t + 1];

    __shared__ float w_lds[2][32][140];   // [buf][k][phys(rl)], skewed
    __shared__ float h_lds[2][32][68];    // [buf][k][s]
    const int tid = threadIdx.x;
    const int tr = tid & 15;              // r-octet
    const int ts = tid >> 4;              // s-quad
    const int ub = blockIdx.y;            // unit-tile (32 units)
    const int scol = s0 + ts * 4;
    const int wphys = tr * 8 + ((tr >> 2) << 2);

    // prefetch epilogue inputs early (independent of GEMM)
    int4 pn = *(const int4*)&perm[scol];
    const int pns[4] = {pn.x, pn.y, pn.z, pn.w};
    int vids[4];
    #pragma unroll
    for (int j = 0; j < 4; ++j) vids[j] = tok[pns[j] * 16 + t];

    float acc[8][4];
    #pragma unroll
    for (int x = 0; x < 8; ++x)
        #pragma unroll
        for (int y = 0; y < 4; ++y) acc[x][y] = 0.f;

    float4 wbuf[4], hbuf[2];
    auto load_t = [&](int k0) {
        #pragma unroll
        for (int p = 0; p < 4; ++p) {
            int idx = tid + p * 256;
            int rl = idx >> 3, k4 = idx & 7;
            int gi = rl & 3, ii = rl >> 2;
            wbuf[p] = *(const float4*)&Whh[(gi * 256 + ub * 32 + ii) * 256 + k0 + k4 * 4];
        }
        #pragma unroll
        for (int p = 0; p < 2; ++p) {
            int idx = tid + p * 256;
            int jj = idx >> 4, s4 = idx & 15;
            hbuf[p] = *(const float4*)&hTprev[(k0 + jj) * 4096 + s0 + s4 * 4];
        }
    };
    auto store_t = [&](int b) {
        #pragma unroll
        for (int p = 0; p < 4; ++p) {
            int idx = tid + p * 256;
            int rl = idx >> 3, k4 = idx & 7;
            int pc = rl + ((rl >> 5) << 2);
            w_lds[b][k4 * 4 + 0][pc] = wbuf[p].x;
            w_lds[b][k4 * 4 + 1][pc] = wbuf[p].y;
            w_lds[b][k4 * 4 + 2][pc] = wbuf[p].z;
            w_lds[b][k4 * 4 + 3][pc] = wbuf[p].w;
        }
        #pragma unroll
        for (int p = 0; p < 2; ++p) {
            int idx = tid + p * 256;
            int jj = idx >> 4, s4 = idx & 15;
            *(float4*)&h_lds[b][jj][s4 * 4] = hbuf[p];
        }
    };

    load_t(0); store_t(0); __syncthreads();
    for (int c = 0; c < 8; ++c) {
        const int b = c & 1;
        if (c < 7) load_t((c + 1) * 32);
        #pragma unroll 4
        for (int k = 0; k < 32; ++k) {
            float4 w0 = *(const float4*)&w_lds[b][k][wphys];
            float4 w1 = *(const float4*)&w_lds[b][k][wphys + 4];
            float4 hv = *(const float4*)&h_lds[b][k][ts * 4];
            float wa[8] = {w0.x, w0.y, w0.z, w0.w, w1.x, w1.y, w1.z, w1.w};
            float ha[4] = {hv.x, hv.y, hv.z, hv.w};
            #pragma unroll
            for (int ri = 0; ri < 8; ++ri)
                #pragma unroll
                for (int si = 0; si < 4; ++si)
                    acc[ri][si] += wa[ri] * ha[si];
        }
        if (c < 7) store_t(b ^ 1);        // other buffer: no WAR hazard
        __syncthreads();                  // one barrier per chunk
    }

    // epilogue: 2 units x 4 slots LSTM update
    #pragma unroll
    for (int half = 0; half < 2; ++half) {
        const int u = ub * 32 + tr * 2 + half;
        float4 cold = *(const float4*)&cT[u * 4096 + scol];
        const float* coldp = (const float*)&cold;
        float c4[4], h4[4];
        #pragma unroll
        for (int j = 0; j < 4; ++j) {
            const float* e = emb2 + vids[j] * 1024 + u;
            float ig = acc[half * 4 + 0][j] + e[0];
            float fg = acc[half * 4 + 1][j] + e[256];
            float gg = acc[half * 4 + 2][j] + e[512];
            float og = acc[half * 4 + 3][j] + e[768];
            float cc = sig_(fg) * coldp[j] + sig_(ig) * th_(gg);
            c4[j] = cc;
            h4[j] = sig_(og) * th_(cc);
            int p = scol + j;
            if (p >= a_t1 && p < a_t)      // len == t+1: last valid step
                featsT[u * 4096 + pns[j]] = h4[j];
        }
        *(float4*)&cT[u * 4096 + scol]     = make_float4(c4[0], c4[1], c4[2], c4[3]);
        *(float4*)&hTnext[u * 4096 + scol] = make_float4(h4[0], h4[1], h4[2], h4[3]);
    }
}

// ---------------------------------------------------------------------------
// T-GEMM 128r x 64s (8x4): Out[r][s] = sum_k W[r][k]*X[k*xstride+s] + add.
// Skewed w-LDS + double-buffered chunks (one barrier/chunk). grid (64, 8).
// Phase-2: X = hTbuf (HSTRIDE, front pad -> X[k][s] = h[k][s-1]).
// ---------------------------------------------------------------------------
__global__ __launch_bounds__(256, 2)
void gemm_T(const float* __restrict__ W, const float* __restrict__ X, int xstride,
            const float* __restrict__ addm, const float* __restrict__ bias,
            float* __restrict__ Out)
{
    __shared__ float w_lds[2][32][140];
    __shared__ float h_lds[2][32][68];
    const int tid = threadIdx.x;
    const int tr = tid & 15;
    const int ts = tid >> 4;
    const int s0 = blockIdx.x * 64;
    const int r0 = blockIdx.y * 128;
    const int wphys = tr * 8 + ((tr >> 2) << 2);

    float acc[8][4];
    #pragma unroll
    for (int x = 0; x < 8; ++x)
        #pragma unroll
        for (int y = 0; y < 4; ++y) acc[x][y] = 0.f;

    float4 wbuf[4], hbuf[2];
    auto load_t = [&](int k0) {
        #pragma unroll
        for (int p = 0; p < 4; ++p) {
            int idx = tid + p * 256;
            int r = idx >> 3, k4 = idx & 7;
            wbuf[p] = *(const float4*)&W[(r0 + r) * 256 + k0 + k4 * 4];
        }
        #pragma unroll
        for (int p = 0; p < 2; ++p) {
            int idx = tid + p * 256;
            int jj = idx >> 4, s4 = idx & 15;
            hbuf[p] = *(const float4*)&X[(k0 + jj) * xstride + s0 + s4 * 4];
        }
    };
    auto store_t = [&](int b) {
        #pragma unroll
        for (int p = 0; p < 4; ++p) {
            int idx = tid + p * 256;
            int rl = idx >> 3, k4 = idx & 7;
            int pc = rl + ((rl >> 5) << 2);
            w_lds[b][k4 * 4 + 0][pc] = wbuf[p].x;
            w_lds[b][k4 * 4 + 1][pc] = wbuf[p].y;
            w_lds[b][k4 * 4 + 2][pc] = wbuf[p].z;
            w_lds[b][k4 * 4 + 3][pc] = wbuf[p].w;
        }
        #pragma unroll
        for (int p = 0; p < 2; ++p) {
            int idx = tid + p * 256;
            int jj = idx >> 4, s4 = idx & 15;
            *(float4*)&h_lds[b][jj][s4 * 4] = hbuf[p];
        }
    };

    load_t(0); store_t(0); __syncthreads();
    for (int c = 0; c < 8; ++c) {
        const int b = c & 1;
        if (c < 7) load_t((c + 1) * 32);
        #pragma unroll 4
        for (int k = 0; k < 32; ++k) {
            float4 w0 = *(const float4*)&w_lds[b][k][wphys];
            float4 w1 = *(const float4*)&w_lds[b][k][wphys + 4];
            float4 hv = *(const float4*)&h_lds[b][k][ts * 4];
            float wa[8] = {w0.x, w0.y, w0.z, w0.w, w1.x, w1.y, w1.z, w1.w};
            float ha[4] = {hv.x, hv.y, hv.z, hv.w};
            #pragma unroll
            for (int ri = 0; ri < 8; ++ri)
                #pragma unroll
                for (int si = 0; si < 4; ++si)
                    acc[ri][si] += wa[ri] * ha[si];
        }
        if (c < 7) store_t(b ^ 1);
        __syncthreads();
    }

    const int scol = s0 + ts * 4;
    #pragma unroll
    for (int ri = 0; ri < 8; ++ri) {
        const int r = r0 + tr * 8 + ri;
        float4 z;
        if (addm) {
            float4 gb = *(const float4*)&addm[r * 4096 + scol];
            z.x = acc[ri][0] + gb.x; z.y = acc[ri][1] + gb.y;
            z.z = acc[ri][2] + gb.z; z.w = acc[ri][3] + gb.w;
        } else {
            float bb = bias[r];
            z.x = acc[ri][0] + bb; z.y = acc[ri][1] + bb;
            z.z = acc[ri][2] + bb; z.w = acc[ri][3] + bb;
        }
        *(float4*)&Out[r * 4096 + scol] = z;
    }
}

// ---------------------------------------------------------------------------
// Sweep scan: exact per-unit affine scan of c given gate preactivations ZT,
// then h = sig(o)*tanh(c) -> hTbuf[u][1+s]. grid 256, block 256.
// ---------------------------------------------------------------------------
__global__ __launch_bounds__(256, 1)
void scan_sweep(const float* __restrict__ ZT, float* __restrict__ hTbuf)
{
    const int u = blockIdx.x;
    const int t = threadIdx.x;
    const int s0 = t * 16;

    const float* zi = ZT + (0 * 256 + u) * 4096 + s0;
    const float* zf = ZT + (1 * 256 + u) * 4096 + s0;
    const float* zg = ZT + (2 * 256 + u) * 4096 + s0;
    const float* zo = ZT + (3 * 256 + u) * 4096 + s0;

    float4 iv[4], fv[4], gv[4], ov[4];
    #pragma unroll
    for (int p = 0; p < 4; ++p) {
        iv[p] = *(const float4*)&zi[p * 4];
        fv[p] = *(const float4*)&zf[p * 4];
        gv[p] = *(const float4*)&zg[p * 4];
        ov[p] = *(const float4*)&zo[p * 4];
    }
    float af[16], uu[16];
    const float* ivp = (const float*)iv;
    const float* fvp = (const float*)fv;
    const float* gvp = (const float*)gv;
    float A = 1.f, U = 0.f;
    #pragma unroll
    for (int k = 0; k < 16; ++k) {
        af[k] = sig_(fvp[k]);
        uu[k] = sig_(ivp[k]) * th_(gvp[k]);
        U = af[k] * U + uu[k];
        A = af[k] * A;
    }

    __shared__ float As[256], Us[256];
    As[t] = A; Us[t] = U;
    __syncthreads();
    #pragma unroll
    for (int off = 1; off < 256; off <<= 1) {
        float eA = 1.f, eU = 0.f;
        if (t >= off) { eA = As[t - off]; eU = Us[t - off]; }
        __syncthreads();
        U = A * eU + U;
        A = A * eA;
        As[t] = A; Us[t] = U;
        __syncthreads();
    }
    float c = (t > 0) ? Us[t - 1] : 0.f;  // exclusive prefix -> entry c

    float* hp = hTbuf + u * HSTRIDE + 1 + s0;
    const float* ovp = (const float*)ov;
    #pragma unroll
    for (int k = 0; k < 16; ++k) {
        c = af[k] * c + uu[k];
        hp[k] = sig_(ovp[k]) * th_(c);
    }
}

// ---------------------------------------------------------------------------
// Final linear: out = h[4095] . lin_W + lin_b
// ---------------------------------------------------------------------------
__global__ __launch_bounds__(256)
void out_kernel(const float* __restrict__ hTbuf, const float* __restrict__ linW,
                const float* __restrict__ linb, float* __restrict__ out)
{
    const int tid = threadIdx.x;
    __shared__ float red_lds[4];
    float p = hTbuf[tid * HSTRIDE + 4096] * linW[tid];
    #pragma unroll
    for (int off = 1; off < 64; off <<= 1) p += __shfl_xor(p, off);
    if ((tid & 63) == 0) red_lds[tid >> 6] = p;
    __syncthreads();
    if (tid == 0)
        out[0] = red_lds[0] + red_lds[1] + red_lds[2] + red_lds[3] + linb[0];
}

extern "C" void kernel_launch(void* const* d_in, const int* in_sizes, int n_in,
                              void* d_out, int out_size, void* d_ws, size_t ws_size,
                              hipStream_t stream)
{
    const int*   tok  = (const int*)d_in[0];
    const int*   len  = (const int*)d_in[1];
    const float* emb  = (const float*)d_in[2];
    const float* tWih = (const float*)d_in[3];
    const float* tWhh = (const float*)d_in[4];
    const float* tb   = (const float*)d_in[5];
    const float* iWih = (const float*)d_in[6];
    const float* iWhh = (const float*)d_in[7];
    const float* ib   = (const float*)d_in[8];
    const float* lW   = (const float*)d_in[9];
    const float* lb   = (const float*)d_in[10];
    float* out = (float*)d_out;

    // workspace (floats), ~44 MB; ZT (phase 2) aliases hT0..featsT (dead)
    float* emb2   = (float*)d_ws;           // [2000][1024]   8 MB
    float* hT0    = emb2   + 2048000;       // [256][4096]    4 MB
    float* hT1    = hT0    + 1048576;       // [256][4096]
    float* cT     = hT1    + 1048576;       // [256][4096]
    float* featsT = cT     + 1048576;       // [256][4096]
    float* gBT    = featsT + 1048576;       // [1024][4096]  16 MB
    float* hTbuf  = gBT    + 4194304;       // [256][HSTRIDE], col0 = 0 pad
    int*   perm   = (int*)(hTbuf + 256 * HSTRIDE);  // [4096]
    int*   actcnt = perm + 4096;            // [17]
    float* ZT     = hT0;                    // [1024][4096] alias (phase 2 only)

    // hTbuf col 0 must be 0 (h[-1])
    hipMemsetAsync(hTbuf, 0, (size_t)256 * HSTRIDE * sizeof(float), stream);

    // ---- phase 1: token LSTM, transposed, length-sorted batch-parallel ----
    sortlen<<<1, 256, 0, stream>>>(len, perm, actcnt);
    gemm_emb2<<<dim3(32, 16), 256, 0, stream>>>(emb, tWih, tb, emb2, 2000);
    step0T<<<dim3(64, 16), 256, 0, stream>>>(tok, perm, actcnt, emb2, cT, hT0,
                                             featsT);
    for (int t = 1; t < 16; ++t) {
        float* hprev = (t & 1) ? hT0 : hT1;
        float* hcur  = (t & 1) ? hT1 : hT0;
        stepT<<<dim3(64, 8), 256, 0, stream>>>(tWhh, hprev, tok, t, emb2, perm,
                                               actcnt, cT, hcur, featsT);
    }
    // gBT[r][s] = ins_W_ih . featsT + ins_b
    gemm_T<<<dim3(64, 8), 256, 0, stream>>>(iWih, featsT, 4096, nullptr, ib, gBT);

    // ---- phase 2: fixed-point sweeps (no cross-block sync) ----
    scan_sweep<<<256, 256, 0, stream>>>(gBT, hTbuf);    // sweep 1: h_old = 0
    for (int k = 1; k < SWEEPS; ++k) {
        gemm_T<<<dim3(64, 8), 256, 0, stream>>>(iWhh, hTbuf, HSTRIDE, gBT,
                                                nullptr, ZT);
        scan_sweep<<<256, 256, 0, stream>>>(ZT, hTbuf);
    }

    out_kernel<<<1, 256, 0, stream>>>(hTbuf, lW, lb, out);
}